// Round 1
// baseline (5265.520 us; speedup 1.0000x reference)
//
#include <hip/hip_runtime.h>
#include <math.h>

// Problem constants (match reference)
constexpr int Bc = 4, Tc = 1024, Cc = 1024, Hc = 16, Dc = 64, SINKc = 4;
constexpr float EPS_LN = 1e-5f;

// ---------------------------------------------------------------------------
// LayerNorm: one 256-thread block per row of C=1024. float4 loads.
// ---------------------------------------------------------------------------
__global__ __launch_bounds__(256) void ln_kernel(
    const float* __restrict__ x, const float* __restrict__ w,
    const float* __restrict__ bsh, float* __restrict__ outp)
{
    int row = blockIdx.x;
    const float* xr = x + (size_t)row * Cc;
    float* orow = outp + (size_t)row * Cc;
    int tid = threadIdx.x;

    float4 xl = reinterpret_cast<const float4*>(xr)[tid];
    float s  = xl.x + xl.y + xl.z + xl.w;
    float s2 = xl.x*xl.x + xl.y*xl.y + xl.z*xl.z + xl.w*xl.w;
    for (int off = 32; off; off >>= 1) {
        s  += __shfl_down(s,  off, 64);
        s2 += __shfl_down(s2, off, 64);
    }
    __shared__ float r1[4], r2[4];
    if ((tid & 63) == 0) { r1[tid >> 6] = s; r2[tid >> 6] = s2; }
    __syncthreads();
    float mu  = (r1[0]+r1[1]+r1[2]+r1[3]) * (1.0f / Cc);
    float var = (r2[0]+r2[1]+r2[2]+r2[3]) * (1.0f / Cc) - mu*mu;
    float rstd = rsqrtf(var + EPS_LN);

    float4 wl = reinterpret_cast<const float4*>(w)[tid];
    float4 bl = reinterpret_cast<const float4*>(bsh)[tid];
    float4 o;
    o.x = (xl.x - mu) * rstd * wl.x + bl.x;
    o.y = (xl.y - mu) * rstd * wl.y + bl.y;
    o.z = (xl.z - mu) * rstd * wl.z + bl.z;
    o.w = (xl.w - mu) * rstd * wl.w + bl.w;
    reinterpret_cast<float4*>(orow)[tid] = o;
}

// ---------------------------------------------------------------------------
// fp32 GEMM: C[M][N] = A[M][K] @ B[K][N] + bias[N], with epilogue:
//   EPI=0: none   EPI=1: exact GELU   EPI=2: + R[m][n] (residual)
// 64x64 tile, BK=16, 256 threads, 4x4 microtile, float4 global+LDS access.
// ---------------------------------------------------------------------------
template <int EPI>
__global__ __launch_bounds__(256) void gemm_f32(
    const float* __restrict__ A, const float* __restrict__ B,
    const float* __restrict__ bias, const float* __restrict__ R,
    float* __restrict__ Cm, int M, int N, int K)
{
    // As is stored transposed [k][m], padded to 68 so rows stay 16B-aligned
    // and the transpose store is only 2-way bank aliased (free on CDNA4).
    __shared__ __align__(16) float As[16][68];
    __shared__ __align__(16) float Bs[16][64];

    int bx = blockIdx.x, by = blockIdx.y;
    int tid = threadIdx.x;
    int tx = tid % 16, ty = tid / 16;      // 16x16 threads, each 4x4 outputs

    float acc[4][4] = {};

    const int a_m = tid / 4;               // 0..63  (row within A tile)
    const int a_k = tid % 4;               // float4 index within 16-wide K
    const int b_k = tid / 16;              // 0..15  (row within B tile)
    const int b_n = tid % 16;              // float4 index within 64-wide N

    const float* Abase = A + (size_t)(by * 64 + a_m) * K + a_k * 4;
    const float* Bbase = B + (size_t)b_k * N + bx * 64 + b_n * 4;

    for (int k0 = 0; k0 < K; k0 += 16) {
        __syncthreads();
        float4 av = *reinterpret_cast<const float4*>(Abase + k0);
        As[a_k*4 + 0][a_m] = av.x;
        As[a_k*4 + 1][a_m] = av.y;
        As[a_k*4 + 2][a_m] = av.z;
        As[a_k*4 + 3][a_m] = av.w;
        float4 bv = *reinterpret_cast<const float4*>(Bbase + (size_t)k0 * N);
        *reinterpret_cast<float4*>(&Bs[b_k][b_n*4]) = bv;
        __syncthreads();

        #pragma unroll
        for (int k = 0; k < 16; k++) {
            float4 a4 = *reinterpret_cast<const float4*>(&As[k][ty*4]);
            float4 b4 = *reinterpret_cast<const float4*>(&Bs[k][tx*4]);
            const float a[4] = {a4.x, a4.y, a4.z, a4.w};
            const float b[4] = {b4.x, b4.y, b4.z, b4.w};
            #pragma unroll
            for (int i = 0; i < 4; i++)
                #pragma unroll
                for (int j = 0; j < 4; j++)
                    acc[i][j] += a[i] * b[j];
        }
    }

    const float4 bias4 = *reinterpret_cast<const float4*>(&bias[bx*64 + tx*4]);
    const float bb[4] = {bias4.x, bias4.y, bias4.z, bias4.w};
    #pragma unroll
    for (int i = 0; i < 4; i++) {
        int m = by * 64 + ty * 4 + i;
        float v[4];
        #pragma unroll
        for (int j = 0; j < 4; j++) {
            float t = acc[i][j] + bb[j];
            if (EPI == 1) t = 0.5f * t * (1.0f + erff(t * 0.70710678118654752f));
            v[j] = t;
        }
        float4 o = make_float4(v[0], v[1], v[2], v[3]);
        if (EPI == 2) {
            float4 r = *reinterpret_cast<const float4*>(
                &R[(size_t)m * N + bx*64 + tx*4]);
            o.x += r.x; o.y += r.y; o.z += r.z; o.w += r.w;
        }
        *reinterpret_cast<float4*>(&Cm[(size_t)m * N + bx*64 + tx*4]) = o;
    }
}

// ---------------------------------------------------------------------------
// Attention pass 1: one block per (b,h,q). Scores in LDS, softmax, PV.
// Saves row max m and row sum l for the imp pass. y written in (B,T,C) layout.
// ---------------------------------------------------------------------------
__global__ __launch_bounds__(256) void attn_fwd(
    const float* __restrict__ qkv, const int* __restrict__ amask,
    float* __restrict__ ybuf, float* __restrict__ mbuf, float* __restrict__ lbuf)
{
    int q  = blockIdx.x % Tc;
    int bh = blockIdx.x / Tc;
    int h  = bh % Hc, b = bh / Hc;
    int tid = threadIdx.x;

    __shared__ float qv[Dc];
    __shared__ float sc[Tc];
    __shared__ float red[8];
    __shared__ float yred[256];

    const size_t rowq = (size_t)(b * Tc + q) * (3 * Cc);
    if (tid < Dc) qv[tid] = qkv[rowq + h * Dc + tid];
    __syncthreads();

    const int nk = q + 1;
    float lmax = -INFINITY;
    for (int k = tid; k < nk; k += 256) {
        float s;
        if (amask[b * Tc + k] == 0) {
            s = -INFINITY;
        } else {
            const float* kv = qkv + (size_t)(b * Tc + k) * (3 * Cc) + Cc + h * Dc;
            float d0 = 0.f;
            #pragma unroll
            for (int d = 0; d < Dc; d++) d0 += qv[d] * kv[d];
            s = d0 * 0.125f;   // 1/sqrt(64)
        }
        sc[k] = s;
        lmax = fmaxf(lmax, s);
    }
    for (int off = 32; off; off >>= 1) lmax = fmaxf(lmax, __shfl_down(lmax, off, 64));
    if ((tid & 63) == 0) red[tid >> 6] = lmax;
    __syncthreads();
    float m = fmaxf(fmaxf(red[0], red[1]), fmaxf(red[2], red[3]));

    float lsum = 0.f;
    if (m > -INFINITY) {
        for (int k = tid; k < nk; k += 256) {
            float s = sc[k];
            float e = (s == -INFINITY) ? 0.f : __expf(s - m);
            sc[k] = e;
            lsum += e;
        }
    } else {
        for (int k = tid; k < nk; k += 256) sc[k] = 0.f;
    }
    for (int off = 32; off; off >>= 1) lsum += __shfl_down(lsum, off, 64);
    if ((tid & 63) == 0) red[4 + (tid >> 6)] = lsum;
    __syncthreads();
    float l = red[4] + red[5] + red[6] + red[7];
    if (tid == 0) { mbuf[(size_t)bh * Tc + q] = m; lbuf[(size_t)bh * Tc + q] = l; }
    float invl = (l > 0.f) ? 1.f / l : 0.f;   // nan_to_num for fully-masked rows

    int d = tid & 63, part = tid >> 6;
    float acc = 0.f;
    const float* vbase = qkv + (size_t)b * Tc * 3 * Cc + 2 * Cc + h * Dc + d;
    for (int k = part; k < nk; k += 4) acc += sc[k] * vbase[(size_t)k * 3 * Cc];
    yred[tid] = acc;
    __syncthreads();
    if (tid < Dc) {
        float y = (yred[d] + yred[64 + d] + yred[128 + d] + yred[192 + d]) * invl;
        ybuf[(size_t)(b * Tc + q) * Cc + h * Dc + d] = y;
    }
}

// ---------------------------------------------------------------------------
// imp pass: one block per (b, key). imp_raw[b,k] = (1/H) sum_h sum_{q>=k}
// exp(s(q,k)-m_q)/l_q  — recomputes QK^T transposed using saved (m,l).
// Also applies pos_norm division.
// ---------------------------------------------------------------------------
__global__ __launch_bounds__(256) void imp_kernel(
    const float* __restrict__ qkv, const int* __restrict__ amask,
    const float* __restrict__ mbuf, const float* __restrict__ lbuf,
    float* __restrict__ impbuf)
{
    int k = blockIdx.x % Tc;
    int b = blockIdx.x / Tc;
    int tid = threadIdx.x;

    __shared__ float kv[Dc];
    __shared__ float red[4];

    float acc = 0.f;
    if (amask[b * Tc + k] != 0) {     // uniform per block
        for (int h = 0; h < Hc; h++) {
            __syncthreads();
            if (tid < Dc)
                kv[tid] = qkv[(size_t)(b * Tc + k) * 3 * Cc + Cc + h * Dc + tid];
            __syncthreads();
            const float* mrow = mbuf + (size_t)(b * Hc + h) * Tc;
            const float* lrow = lbuf + (size_t)(b * Hc + h) * Tc;
            for (int q = k + tid; q < Tc; q += 256) {
                float l = lrow[q];
                if (l > 0.f) {
                    const float* qr = qkv + (size_t)(b * Tc + q) * 3 * Cc + h * Dc;
                    float d0 = 0.f;
                    #pragma unroll
                    for (int d = 0; d < Dc; d++) d0 += kv[d] * qr[d];
                    acc += __expf(d0 * 0.125f - mrow[q]) / l;
                }
            }
        }
    }
    for (int off = 32; off; off >>= 1) acc += __shfl_down(acc, off, 64);
    if ((tid & 63) == 0) red[tid >> 6] = acc;
    __syncthreads();
    if (tid == 0) {
        float tot = (red[0] + red[1] + red[2] + red[3]) * (1.0f / Hc);
        float posn = (float)(Tc - k) / (float)Tc;
        impbuf[b * Tc + k] = tot / (posn + 1e-8f);
    }
}

// ---------------------------------------------------------------------------
// Finalize: global max of imp (no axis in reference!), sink fill, threshold
// mask, attention_mask multiply. Single block.
// ---------------------------------------------------------------------------
__global__ __launch_bounds__(1024) void finalize_kernel(
    const float* __restrict__ impbuf, const int* __restrict__ amask,
    const float* __restrict__ thr, float* __restrict__ out_mask,
    float* __restrict__ out_imp)
{
    __shared__ float red[16];
    int tid = threadIdx.x;
    float gmax = -INFINITY;
    for (int i = tid; i < Bc * Tc; i += 1024) gmax = fmaxf(gmax, impbuf[i]);
    for (int off = 32; off; off >>= 1) gmax = fmaxf(gmax, __shfl_down(gmax, off, 64));
    if ((tid & 63) == 0) red[tid >> 6] = gmax;
    __syncthreads();
    float gm = red[0];
    #pragma unroll
    for (int i = 1; i < 16; i++) gm = fmaxf(gm, red[i]);

    float t = thr[0];
    for (int i = tid; i < Bc * Tc; i += 1024) {
        int tt = i % Tc;
        float v = impbuf[i];
        if (tt < SINKc) v = gm + 1.0f;
        float mk = (v >= t) ? 1.f : 0.f;
        if (tt < SINKc) mk = 1.f;
        mk *= (float)amask[i];
        out_imp[i]  = v;
        out_mask[i] = mk;
    }
}

// ---------------------------------------------------------------------------
extern "C" void kernel_launch(void* const* d_in, const int* in_sizes, int n_in,
                              void* d_out, int out_size, void* d_ws, size_t ws_size,
                              hipStream_t stream)
{
    const float* x      = (const float*)d_in[0];
    const int*   amask  = (const int*)  d_in[1];
    const float* W_attn = (const float*)d_in[2];
    const float* b_attn = (const float*)d_in[3];
    const float* W_proj = (const float*)d_in[4];
    const float* b_proj = (const float*)d_in[5];
    const float* ln1w   = (const float*)d_in[6];
    const float* ln1b   = (const float*)d_in[7];
    const float* ln2w   = (const float*)d_in[8];
    const float* ln2b   = (const float*)d_in[9];
    const float* W_fc   = (const float*)d_in[10];
    const float* b_fc   = (const float*)d_in[11];
    const float* W_fc2  = (const float*)d_in[12];
    const float* b_fc2  = (const float*)d_in[13];
    const float* thr    = (const float*)d_in[14];

    float* out      = (float*)d_out;                 // (B,T,C)
    float* out_mask = out + (size_t)Bc * Tc * Cc;    // (B,T)
    float* out_imp  = out_mask + (size_t)Bc * Tc;    // (B,T)

    float* ws   = (float*)d_ws;
    float* h    = ws;                                // 4,194,304  (ln1 out; reused for ln2 out)
    float* qkv  = ws + 4194304;                      // 12,582,912
    float* y    = ws + 16777216;                     // 4,194,304
    float* fc   = ws + 20971520;                     // 16,777,216
    float* mbuf = ws + 37748736;                     // 65,536
    float* lbuf = ws + 37814272;                     // 65,536
    float* impb = ws + 37879808;                     // 4,096

    const int M = Bc * Tc;   // 4096

    // h = ln1(x)
    ln_kernel<<<M, 256, 0, stream>>>(x, ln1w, ln1b, h);
    // qkv = h @ W_attn + b_attn
    gemm_f32<0><<<dim3(3 * Cc / 64, M / 64), 256, 0, stream>>>(
        h, W_attn, b_attn, nullptr, qkv, M, 3 * Cc, Cc);
    // attention -> y, (m,l)
    attn_fwd<<<Bc * Hc * Tc, 256, 0, stream>>>(qkv, amask, y, mbuf, lbuf);
    // x2 = x + y @ W_proj + b_proj   (into d_out)
    gemm_f32<2><<<dim3(Cc / 64, M / 64), 256, 0, stream>>>(
        y, W_proj, b_proj, x, out, M, Cc, Cc);
    // imp (independent of MLP path)
    imp_kernel<<<Bc * Tc, 256, 0, stream>>>(qkv, amask, mbuf, lbuf, impb);
    // m = ln2(x2)  (reuse h)
    ln_kernel<<<M, 256, 0, stream>>>(out, ln2w, ln2b, h);
    // fc = gelu(m @ W_fc + b_fc)
    gemm_f32<1><<<dim3(4 * Cc / 64, M / 64), 256, 0, stream>>>(
        h, W_fc, b_fc, nullptr, fc, M, 4 * Cc, Cc);
    // out = x2 + fc @ W_fc2 + b_fc2   (in-place residual from d_out)
    gemm_f32<2><<<dim3(Cc / 64, M / 64), 256, 0, stream>>>(
        fc, W_fc2, b_fc2, out, out, M, Cc, 4 * Cc);
    // mask & imp outputs
    finalize_kernel<<<1, 1024, 0, stream>>>(impb, amask, thr, out_mask, out_imp);
}

// Round 2
// 1919.751 us; speedup vs baseline: 2.7428x; 2.7428x over previous
//
#include <hip/hip_runtime.h>
#include <math.h>

// Problem constants (match reference)
constexpr int Bc = 4, Tc = 1024, Cc = 1024, Hc = 16, Dc = 64, SINKc = 4;
constexpr float EPS_LN = 1e-5f;

// ---------------------------------------------------------------------------
// LayerNorm: one 256-thread block per row of C=1024. float4 loads.
// ---------------------------------------------------------------------------
__global__ __launch_bounds__(256) void ln_kernel(
    const float* __restrict__ x, const float* __restrict__ w,
    const float* __restrict__ bsh, float* __restrict__ outp)
{
    int row = blockIdx.x;
    const float* xr = x + (size_t)row * Cc;
    float* orow = outp + (size_t)row * Cc;
    int tid = threadIdx.x;

    float4 xl = reinterpret_cast<const float4*>(xr)[tid];
    float s  = xl.x + xl.y + xl.z + xl.w;
    float s2 = xl.x*xl.x + xl.y*xl.y + xl.z*xl.z + xl.w*xl.w;
    for (int off = 32; off; off >>= 1) {
        s  += __shfl_down(s,  off, 64);
        s2 += __shfl_down(s2, off, 64);
    }
    __shared__ float r1[4], r2[4];
    if ((tid & 63) == 0) { r1[tid >> 6] = s; r2[tid >> 6] = s2; }
    __syncthreads();
    float mu  = (r1[0]+r1[1]+r1[2]+r1[3]) * (1.0f / Cc);
    float var = (r2[0]+r2[1]+r2[2]+r2[3]) * (1.0f / Cc) - mu*mu;
    float rstd = rsqrtf(var + EPS_LN);

    float4 wl = reinterpret_cast<const float4*>(w)[tid];
    float4 bl = reinterpret_cast<const float4*>(bsh)[tid];
    float4 o;
    o.x = (xl.x - mu) * rstd * wl.x + bl.x;
    o.y = (xl.y - mu) * rstd * wl.y + bl.y;
    o.z = (xl.z - mu) * rstd * wl.z + bl.z;
    o.w = (xl.w - mu) * rstd * wl.w + bl.w;
    reinterpret_cast<float4*>(orow)[tid] = o;
}

// ---------------------------------------------------------------------------
// fp32 GEMM: C[M][N] = A[M][K] @ B[K][N] + bias[N], with epilogue:
//   EPI=0: none   EPI=1: exact GELU   EPI=2: + R[m][n] (residual)
// 64x64 tile, BK=16, 256 threads, 4x4 microtile, float4 global+LDS access.
// ---------------------------------------------------------------------------
template <int EPI>
__global__ __launch_bounds__(256) void gemm_f32(
    const float* __restrict__ A, const float* __restrict__ B,
    const float* __restrict__ bias, const float* __restrict__ R,
    float* __restrict__ Cm, int M, int N, int K)
{
    __shared__ __align__(16) float As[16][68];
    __shared__ __align__(16) float Bs[16][64];

    int bx = blockIdx.x, by = blockIdx.y;
    int tid = threadIdx.x;
    int tx = tid % 16, ty = tid / 16;

    float acc[4][4] = {};

    const int a_m = tid / 4;
    const int a_k = tid % 4;
    const int b_k = tid / 16;
    const int b_n = tid % 16;

    const float* Abase = A + (size_t)(by * 64 + a_m) * K + a_k * 4;
    const float* Bbase = B + (size_t)b_k * N + bx * 64 + b_n * 4;

    for (int k0 = 0; k0 < K; k0 += 16) {
        __syncthreads();
        float4 av = *reinterpret_cast<const float4*>(Abase + k0);
        As[a_k*4 + 0][a_m] = av.x;
        As[a_k*4 + 1][a_m] = av.y;
        As[a_k*4 + 2][a_m] = av.z;
        As[a_k*4 + 3][a_m] = av.w;
        float4 bv = *reinterpret_cast<const float4*>(Bbase + (size_t)k0 * N);
        *reinterpret_cast<float4*>(&Bs[b_k][b_n*4]) = bv;
        __syncthreads();

        #pragma unroll
        for (int k = 0; k < 16; k++) {
            float4 a4 = *reinterpret_cast<const float4*>(&As[k][ty*4]);
            float4 b4 = *reinterpret_cast<const float4*>(&Bs[k][tx*4]);
            const float a[4] = {a4.x, a4.y, a4.z, a4.w};
            const float b[4] = {b4.x, b4.y, b4.z, b4.w};
            #pragma unroll
            for (int i = 0; i < 4; i++)
                #pragma unroll
                for (int j = 0; j < 4; j++)
                    acc[i][j] += a[i] * b[j];
        }
    }

    const float4 bias4 = *reinterpret_cast<const float4*>(&bias[bx*64 + tx*4]);
    const float bb[4] = {bias4.x, bias4.y, bias4.z, bias4.w};
    #pragma unroll
    for (int i = 0; i < 4; i++) {
        int m = by * 64 + ty * 4 + i;
        float v[4];
        #pragma unroll
        for (int j = 0; j < 4; j++) {
            float t = acc[i][j] + bb[j];
            if (EPI == 1) t = 0.5f * t * (1.0f + erff(t * 0.70710678118654752f));
            v[j] = t;
        }
        float4 o = make_float4(v[0], v[1], v[2], v[3]);
        if (EPI == 2) {
            float4 r = *reinterpret_cast<const float4*>(
                &R[(size_t)m * N + bx*64 + tx*4]);
            o.x += r.x; o.y += r.y; o.z += r.z; o.w += r.w;
        }
        *reinterpret_cast<float4*>(&Cm[(size_t)m * N + bx*64 + tx*4]) = o;
    }
}

// ---------------------------------------------------------------------------
// Flash attention: one block per (b,h,qtile of 64). 256 threads, 4x4 micro.
// LDS: Qt[d][q] (transposed), KP[d][k] (K transposed; reused for P[q][k]
// after S GEMM), Vs[k][d] (plain). Online softmax with (m,l) saved to
// mbuf/lbuf for the imp pass. All GEMM-phase LDS reads are 2-way/broadcast.
// ---------------------------------------------------------------------------
__global__ __launch_bounds__(256) void attn_flash(
    const float* __restrict__ qkv, const int* __restrict__ amask,
    float* __restrict__ ybuf, float* __restrict__ mbuf, float* __restrict__ lbuf)
{
    constexpr int PW = 68;
    __shared__ __align__(16) float Qt[64][PW];   // Qt[d][q]
    __shared__ __align__(16) float KP[64][PW];   // Kt[d][k], then Ps[q][k]
    __shared__ __align__(16) float Vs[64][PW];   // Vs[k][d]

    int blk = blockIdx.x;
    int qt = blk & 15;
    int h  = (blk >> 4) & 15;
    int b  = blk >> 8;
    int q0 = qt * 64;

    int tid = threadIdx.x;
    int tx = tid & 15, ty = tid >> 4;
    int lr = tid >> 4;                     // staging row within pass
    const size_t bbase = (size_t)b * Tc * 3 * Cc;

    // Stage Q tile transposed (once)
    #pragma unroll
    for (int p = 0; p < 4; p++) {
        int r = p * 16 + lr;
        float4 v = *(const float4*)(qkv + bbase + (size_t)(q0 + r) * 3*Cc + h*64 + tx*4);
        Qt[tx*4+0][r] = v.x; Qt[tx*4+1][r] = v.y;
        Qt[tx*4+2][r] = v.z; Qt[tx*4+3][r] = v.w;
    }

    float m_i[4], l_i[4], O[4][4];
    #pragma unroll
    for (int i = 0; i < 4; i++) {
        m_i[i] = -INFINITY; l_i[i] = 0.f;
        #pragma unroll
        for (int j = 0; j < 4; j++) O[i][j] = 0.f;
    }

    for (int kt = 0; kt <= qt; kt++) {
        int k0 = kt * 64;
        __syncthreads();                   // protect prev-iter KP(P)/Vs reads
        #pragma unroll
        for (int p = 0; p < 4; p++) {
            int r = p * 16 + lr;
            float4 k4 = *(const float4*)(qkv + bbase + (size_t)(k0 + r)*3*Cc + Cc + h*64 + tx*4);
            KP[tx*4+0][r] = k4.x; KP[tx*4+1][r] = k4.y;
            KP[tx*4+2][r] = k4.z; KP[tx*4+3][r] = k4.w;
            float4 v4 = *(const float4*)(qkv + bbase + (size_t)(k0 + r)*3*Cc + 2*Cc + h*64 + tx*4);
            *(float4*)&Vs[r][tx*4] = v4;
        }
        __syncthreads();

        // S tile = Q K^T  (64x64x64)
        float acc[4][4] = {};
        #pragma unroll 8
        for (int d = 0; d < 64; d++) {
            float4 q4 = *(const float4*)&Qt[d][ty*4];
            float4 k4 = *(const float4*)&KP[d][tx*4];
            const float qa[4] = {q4.x, q4.y, q4.z, q4.w};
            const float ka[4] = {k4.x, k4.y, k4.z, k4.w};
            #pragma unroll
            for (int i = 0; i < 4; i++)
                #pragma unroll
                for (int j = 0; j < 4; j++)
                    acc[i][j] += qa[i] * ka[j];
        }

        int am[4];
        #pragma unroll
        for (int j = 0; j < 4; j++) am[j] = amask[b*Tc + k0 + tx*4 + j];

        __syncthreads();                   // all S reads of KP done before P write

        float pv[4][4];
        float alpha[4];
        #pragma unroll
        for (int i = 0; i < 4; i++) {
            int qg = q0 + ty*4 + i;
            float s[4];
            float rmax = -INFINITY;
            #pragma unroll
            for (int j = 0; j < 4; j++) {
                int kg = k0 + tx*4 + j;
                s[j] = (kg <= qg && am[j] != 0) ? acc[i][j] * 0.125f : -INFINITY;
                rmax = fmaxf(rmax, s[j]);
            }
            #pragma unroll
            for (int off = 8; off; off >>= 1)
                rmax = fmaxf(rmax, __shfl_xor(rmax, off, 16));
            float mnew = fmaxf(m_i[i], rmax);
            alpha[i] = (m_i[i] == -INFINITY) ? 0.f : __expf(m_i[i] - mnew);
            float rsum = 0.f;
            #pragma unroll
            for (int j = 0; j < 4; j++) {
                pv[i][j] = (s[j] == -INFINITY) ? 0.f : __expf(s[j] - mnew);
                rsum += pv[i][j];
            }
            #pragma unroll
            for (int off = 8; off; off >>= 1)
                rsum += __shfl_xor(rsum, off, 16);
            l_i[i] = alpha[i] * l_i[i] + rsum;
            m_i[i] = mnew;
            *(float4*)&KP[ty*4+i][tx*4] = make_float4(pv[i][0], pv[i][1], pv[i][2], pv[i][3]);
            #pragma unroll
            for (int j = 0; j < 4; j++) O[i][j] *= alpha[i];
        }
        __syncthreads();                   // P visible before PV

        // O += P V  (64x64x64)
        #pragma unroll 4
        for (int kc = 0; kc < 16; kc++) {
            float pa[4][4], va[4][4];
            #pragma unroll
            for (int i = 0; i < 4; i++) {
                float4 t4 = *(const float4*)&KP[ty*4+i][kc*4];
                pa[i][0] = t4.x; pa[i][1] = t4.y; pa[i][2] = t4.z; pa[i][3] = t4.w;
            }
            #pragma unroll
            for (int kk = 0; kk < 4; kk++) {
                float4 t4 = *(const float4*)&Vs[kc*4+kk][tx*4];
                va[kk][0] = t4.x; va[kk][1] = t4.y; va[kk][2] = t4.z; va[kk][3] = t4.w;
            }
            #pragma unroll
            for (int i = 0; i < 4; i++)
                #pragma unroll
                for (int kk = 0; kk < 4; kk++)
                    #pragma unroll
                    for (int jd = 0; jd < 4; jd++)
                        O[i][jd] += pa[i][kk] * va[kk][jd];
        }
    }

    #pragma unroll
    for (int i = 0; i < 4; i++) {
        int qg = q0 + ty*4 + i;
        float invl = (l_i[i] > 0.f) ? 1.f / l_i[i] : 0.f;
        float4 o = make_float4(O[i][0]*invl, O[i][1]*invl, O[i][2]*invl, O[i][3]*invl);
        *(float4*)(ybuf + (size_t)(b*Tc + qg) * Cc + h*64 + tx*4) = o;
        if (tx == 0) {
            mbuf[(size_t)(b*Hc + h)*Tc + qg] = m_i[i];
            lbuf[(size_t)(b*Hc + h)*Tc + qg] = l_i[i];
        }
    }
}

// ---------------------------------------------------------------------------
// imp pass, tiled: one block per (b,h,ktile of 64). Accumulates
// sum_{q>=k} exp(s-m_q)/l_q into impbuf[b][k] via atomicAdd (impbuf zeroed
// by hipMemsetAsync). S'[k][q] tile GEMM from LDS, m/l staged per q-tile.
// ---------------------------------------------------------------------------
__global__ __launch_bounds__(256) void imp_flash(
    const float* __restrict__ qkv, const int* __restrict__ amask,
    const float* __restrict__ mbuf, const float* __restrict__ lbuf,
    float* __restrict__ impbuf)
{
    constexpr int PW = 68;
    __shared__ __align__(16) float Kt[64][PW];   // Kt[d][k]
    __shared__ __align__(16) float Qt[64][PW];   // Qt[d][q]
    __shared__ float mls[64], rls[64];

    int blk = blockIdx.x;
    int ktile = blk & 15;
    int h = (blk >> 4) & 15;
    int b = blk >> 8;
    int k0 = ktile * 64;
    int tid = threadIdx.x, tx = tid & 15, ty = tid >> 4;
    int lr = tid >> 4;
    const size_t bbase = (size_t)b * Tc * 3 * Cc;

    #pragma unroll
    for (int p = 0; p < 4; p++) {
        int r = p * 16 + lr;
        float4 k4 = *(const float4*)(qkv + bbase + (size_t)(k0 + r)*3*Cc + Cc + h*64 + tx*4);
        Kt[tx*4+0][r] = k4.x; Kt[tx*4+1][r] = k4.y;
        Kt[tx*4+2][r] = k4.z; Kt[tx*4+3][r] = k4.w;
    }
    int am[4];
    #pragma unroll
    for (int i = 0; i < 4; i++) am[i] = amask[b*Tc + k0 + ty*4 + i];

    float sums[4] = {0.f, 0.f, 0.f, 0.f};

    for (int qt = ktile; qt < 16; qt++) {
        int q0 = qt * 64;
        __syncthreads();                   // protect prev Qt/mls reads
        #pragma unroll
        for (int p = 0; p < 4; p++) {
            int r = p * 16 + lr;
            float4 q4 = *(const float4*)(qkv + bbase + (size_t)(q0 + r)*3*Cc + h*64 + tx*4);
            Qt[tx*4+0][r] = q4.x; Qt[tx*4+1][r] = q4.y;
            Qt[tx*4+2][r] = q4.z; Qt[tx*4+3][r] = q4.w;
        }
        if (tid < 64) {
            float l = lbuf[(size_t)(b*Hc + h)*Tc + q0 + tid];
            mls[tid] = mbuf[(size_t)(b*Hc + h)*Tc + q0 + tid];
            rls[tid] = (l > 0.f) ? 1.f / l : 0.f;
        }
        __syncthreads();

        float acc[4][4] = {};
        #pragma unroll 8
        for (int d = 0; d < 64; d++) {
            float4 k4 = *(const float4*)&Kt[d][ty*4];
            float4 q4 = *(const float4*)&Qt[d][tx*4];
            const float ka[4] = {k4.x, k4.y, k4.z, k4.w};
            const float qa[4] = {q4.x, q4.y, q4.z, q4.w};
            #pragma unroll
            for (int i = 0; i < 4; i++)
                #pragma unroll
                for (int j = 0; j < 4; j++)
                    acc[i][j] += ka[i] * qa[j];
        }

        #pragma unroll
        for (int i = 0; i < 4; i++) {
            if (!am[i]) continue;
            int kg = k0 + ty*4 + i;
            #pragma unroll
            for (int j = 0; j < 4; j++) {
                int qg = q0 + tx*4 + j;
                float rl = rls[tx*4 + j];
                if (kg <= qg && rl > 0.f)
                    sums[i] += __expf(acc[i][j] * 0.125f - mls[tx*4 + j]) * rl;
            }
        }
    }

    #pragma unroll
    for (int i = 0; i < 4; i++) {
        float s = sums[i];
        #pragma unroll
        for (int off = 8; off; off >>= 1) s += __shfl_xor(s, off, 16);
        if (tx == 0) atomicAdd(&impbuf[b*Tc + k0 + ty*4 + i], s);
    }
}

// ---------------------------------------------------------------------------
// Finalize: scale raw sums by 1/H and pos_norm, global max, sinks, mask.
// Single block of 1024; each thread owns exactly 4 elements (kept in regs).
// ---------------------------------------------------------------------------
__global__ __launch_bounds__(1024) void finalize_kernel(
    const float* __restrict__ impbuf, const int* __restrict__ amask,
    const float* __restrict__ thr, float* __restrict__ out_mask,
    float* __restrict__ out_imp)
{
    __shared__ float red[16];
    int tid = threadIdx.x;
    float vloc[4];
    float gmax = -INFINITY;
    #pragma unroll
    for (int it = 0; it < 4; it++) {
        int i = tid + it * 1024;
        int tt = i % Tc;
        float posn = (float)(Tc - tt) / (float)Tc;
        float v = impbuf[i] * (1.0f / Hc) / (posn + 1e-8f);
        vloc[it] = v;
        gmax = fmaxf(gmax, v);
    }
    for (int off = 32; off; off >>= 1) gmax = fmaxf(gmax, __shfl_down(gmax, off, 64));
    if ((tid & 63) == 0) red[tid >> 6] = gmax;
    __syncthreads();
    float gm = red[0];
    #pragma unroll
    for (int i = 1; i < 16; i++) gm = fmaxf(gm, red[i]);

    float t = thr[0];
    #pragma unroll
    for (int it = 0; it < 4; it++) {
        int i = tid + it * 1024;
        int tt = i % Tc;
        float v = vloc[it];
        if (tt < SINKc) v = gm + 1.0f;
        float mk = (v >= t) ? 1.f : 0.f;
        if (tt < SINKc) mk = 1.f;
        mk *= (float)amask[i];
        out_imp[i]  = v;
        out_mask[i] = mk;
    }
}

// ---------------------------------------------------------------------------
extern "C" void kernel_launch(void* const* d_in, const int* in_sizes, int n_in,
                              void* d_out, int out_size, void* d_ws, size_t ws_size,
                              hipStream_t stream)
{
    const float* x      = (const float*)d_in[0];
    const int*   amask  = (const int*)  d_in[1];
    const float* W_attn = (const float*)d_in[2];
    const float* b_attn = (const float*)d_in[3];
    const float* W_proj = (const float*)d_in[4];
    const float* b_proj = (const float*)d_in[5];
    const float* ln1w   = (const float*)d_in[6];
    const float* ln1b   = (const float*)d_in[7];
    const float* ln2w   = (const float*)d_in[8];
    const float* ln2b   = (const float*)d_in[9];
    const float* W_fc   = (const float*)d_in[10];
    const float* b_fc   = (const float*)d_in[11];
    const float* W_fc2  = (const float*)d_in[12];
    const float* b_fc2  = (const float*)d_in[13];
    const float* thr    = (const float*)d_in[14];

    float* out      = (float*)d_out;                 // (B,T,C)
    float* out_mask = out + (size_t)Bc * Tc * Cc;    // (B,T)
    float* out_imp  = out_mask + (size_t)Bc * Tc;    // (B,T)

    float* ws   = (float*)d_ws;
    float* h    = ws;                                // ln1 out; reused for ln2 out
    float* qkv  = ws + 4194304;
    float* y    = ws + 16777216;
    float* fc   = ws + 20971520;
    float* mbuf = ws + 37748736;
    float* lbuf = ws + 37814272;
    float* impb = ws + 37879808;

    const int M = Bc * Tc;   // 4096

    // h = ln1(x)
    ln_kernel<<<M, 256, 0, stream>>>(x, ln1w, ln1b, h);
    // qkv = h @ W_attn + b_attn
    gemm_f32<0><<<dim3(3 * Cc / 64, M / 64), 256, 0, stream>>>(
        h, W_attn, b_attn, nullptr, qkv, M, 3 * Cc, Cc);
    // zero the imp accumulator (ws is poisoned before every call)
    hipMemsetAsync(impb, 0, (size_t)Bc * Tc * sizeof(float), stream);
    // attention -> y, (m,l)
    attn_flash<<<Bc * Hc * (Tc / 64), 256, 0, stream>>>(qkv, amask, y, mbuf, lbuf);
    // x2 = x + y @ W_proj + b_proj   (into d_out)
    gemm_f32<2><<<dim3(Cc / 64, M / 64), 256, 0, stream>>>(
        y, W_proj, b_proj, x, out, M, Cc, Cc);
    // imp accumulation (needs mbuf/lbuf)
    imp_flash<<<Bc * Hc * (Tc / 64), 256, 0, stream>>>(qkv, amask, mbuf, lbuf, impb);
    // m = ln2(x2)  (reuse h)
    ln_kernel<<<M, 256, 0, stream>>>(out, ln2w, ln2b, h);
    // fc = gelu(m @ W_fc + b_fc)
    gemm_f32<1><<<dim3(4 * Cc / 64, M / 64), 256, 0, stream>>>(
        h, W_fc, b_fc, nullptr, fc, M, 4 * Cc, Cc);
    // out = x2 + fc @ W_fc2 + b_fc2   (in-place residual from d_out)
    gemm_f32<2><<<dim3(Cc / 64, M / 64), 256, 0, stream>>>(
        fc, W_fc2, b_fc2, out, out, M, Cc, 4 * Cc);
    // mask & imp outputs
    finalize_kernel<<<1, 1024, 0, stream>>>(impb, amask, thr, out_mask, out_imp);
}

// Round 3
// 787.807 us; speedup vs baseline: 6.6838x; 2.4368x over previous
//
#include <hip/hip_runtime.h>
#include <math.h>

// Problem constants (match reference)
constexpr int Bc = 4, Tc = 1024, Cc = 1024, Hc = 16, Dc = 64, SINKc = 4;
constexpr float EPS_LN = 1e-5f;

typedef __bf16 bf16x4 __attribute__((ext_vector_type(4)));
typedef __bf16 bf16x8 __attribute__((ext_vector_type(8)));
typedef float  f32x4  __attribute__((ext_vector_type(4)));

// ---------------------------------------------------------------------------
// Transpose + fp32->bf16 convert: W[K][N] -> Wt[N][K]. 32x32 tiles.
// ---------------------------------------------------------------------------
__global__ __launch_bounds__(256) void transpose_bf16(
    const float* __restrict__ W, __bf16* __restrict__ Wt, int K, int N)
{
    __shared__ float S[32][33];
    int n0 = blockIdx.x * 32, k0 = blockIdx.y * 32;
    int t = threadIdx.x;
    int r = t >> 3, c4 = (t & 7) * 4;
    float4 v = *(const float4*)(W + (size_t)(k0 + r) * N + n0 + c4);
    S[r][c4+0] = v.x; S[r][c4+1] = v.y; S[r][c4+2] = v.z; S[r][c4+3] = v.w;
    __syncthreads();
    bf16x4 o = { (__bf16)S[c4+0][r], (__bf16)S[c4+1][r],
                 (__bf16)S[c4+2][r], (__bf16)S[c4+3][r] };
    *(bf16x4*)(Wt + (size_t)(n0 + r) * K + k0 + c4) = o;
}

// ---------------------------------------------------------------------------
// LayerNorm: one 256-thread block per row of C=1024. Writes bf16.
// ---------------------------------------------------------------------------
__global__ __launch_bounds__(256) void ln_kernel(
    const float* __restrict__ x, const float* __restrict__ w,
    const float* __restrict__ bsh, __bf16* __restrict__ outp)
{
    int row = blockIdx.x;
    const float* xr = x + (size_t)row * Cc;
    int tid = threadIdx.x;

    float4 xl = reinterpret_cast<const float4*>(xr)[tid];
    float s  = xl.x + xl.y + xl.z + xl.w;
    float s2 = xl.x*xl.x + xl.y*xl.y + xl.z*xl.z + xl.w*xl.w;
    for (int off = 32; off; off >>= 1) {
        s  += __shfl_down(s,  off, 64);
        s2 += __shfl_down(s2, off, 64);
    }
    __shared__ float r1[4], r2[4];
    if ((tid & 63) == 0) { r1[tid >> 6] = s; r2[tid >> 6] = s2; }
    __syncthreads();
    float mu  = (r1[0]+r1[1]+r1[2]+r1[3]) * (1.0f / Cc);
    float var = (r2[0]+r2[1]+r2[2]+r2[3]) * (1.0f / Cc) - mu*mu;
    float rstd = rsqrtf(var + EPS_LN);

    float4 wl = reinterpret_cast<const float4*>(w)[tid];
    float4 bl = reinterpret_cast<const float4*>(bsh)[tid];
    bf16x4 o = { (__bf16)((xl.x - mu) * rstd * wl.x + bl.x),
                 (__bf16)((xl.y - mu) * rstd * wl.y + bl.y),
                 (__bf16)((xl.z - mu) * rstd * wl.z + bl.z),
                 (__bf16)((xl.w - mu) * rstd * wl.w + bl.w) };
    *(bf16x4*)(outp + (size_t)row * Cc + tid * 4) = o;
}

// ---------------------------------------------------------------------------
// bf16 MFMA GEMM: C[M][N] = A[M][K] @ Bt[N][K]^T + bias[N]
//   EPI=0: none   EPI=1: exact GELU   EPI=2: + R[m][n] (fp32 residual)
// 128x128 tile, BK=32, 256 threads (4 waves 2x2, each 64x64 via 4x4 MFMA
// tiles of 16x16x32). global_load_lds width=16 staging; LDS chunk index
// XOR-swizzled with (row>>1)&3 so fragment ds_read_b128 is 2-way (free).
// ---------------------------------------------------------------------------
template <int EPI, typename OutT>
__global__ __launch_bounds__(256) void gemm_bf16(
    const __bf16* __restrict__ A, const __bf16* __restrict__ Bt,
    const float* __restrict__ bias, const float* R,
    OutT* Cm, int M, int N, int K)
{
    __shared__ __bf16 As[128 * 32];   // [row][32] bf16, 8 KB, chunk-swizzled
    __shared__ __bf16 Bs[128 * 32];

    const int tid  = threadIdx.x;
    const int wave = tid >> 6, lane = tid & 63;
    const int wm = wave >> 1, wn = wave & 1;
    const int lr = lane & 15, lc = lane >> 4;     // frag row / k-chunk
    const int bx = blockIdx.x, by = blockIdx.y;

    f32x4 acc[4][4] = {};

    // staging roles: instruction idx = wave*2+t covers tile rows idx*16..+16
    const int srow = lane >> 2;          // row within 16-row group
    const int cphys = lane & 3;          // physical 16B chunk this lane fills

    for (int k0 = 0; k0 < K; k0 += 32) {
        __syncthreads();
        #pragma unroll
        for (int t = 0; t < 2; t++) {
            int idx  = wave * 2 + t;
            int rloc = idx * 16 + srow;                    // 0..127
            int clog = (cphys - (rloc >> 1)) & 3;          // logical chunk
            const __bf16* ga = A  + (size_t)(by * 128 + rloc) * K + k0 + clog * 8;
            const __bf16* gb = Bt + (size_t)(bx * 128 + rloc) * K + k0 + clog * 8;
            __builtin_amdgcn_global_load_lds(
                (const __attribute__((address_space(1))) void*)ga,
                (__attribute__((address_space(3))) void*)(As + idx * 512), 16, 0, 0);
            __builtin_amdgcn_global_load_lds(
                (const __attribute__((address_space(1))) void*)gb,
                (__attribute__((address_space(3))) void*)(Bs + idx * 512), 16, 0, 0);
        }
        __syncthreads();

        bf16x8 af[4], bfr[4];
        #pragma unroll
        for (int i = 0; i < 4; i++) {
            int ra = wm * 64 + i * 16 + lr;
            int ca = (lc + (ra >> 1)) & 3;
            af[i]  = *(const bf16x8*)(As + ra * 32 + ca * 8);
            int rb = wn * 64 + i * 16 + lr;
            int cb = (lc + (rb >> 1)) & 3;
            bfr[i] = *(const bf16x8*)(Bs + rb * 32 + cb * 8);
        }
        #pragma unroll
        for (int i = 0; i < 4; i++)
            #pragma unroll
            for (int j = 0; j < 4; j++)
                acc[i][j] = __builtin_amdgcn_mfma_f32_16x16x32_bf16(
                    af[i], bfr[j], acc[i][j], 0, 0, 0);
    }

    // Epilogue. D layout: col = lane&15, row = (lane>>4)*4 + reg.
    #pragma unroll
    for (int j = 0; j < 4; j++) {
        int n = bx * 128 + wn * 64 + j * 16 + lr;
        float bv = bias[n];
        #pragma unroll
        for (int i = 0; i < 4; i++) {
            int m0 = by * 128 + wm * 64 + i * 16 + lc * 4;
            #pragma unroll
            for (int e = 0; e < 4; e++) {
                float t = acc[i][j][e] + bv;
                if (EPI == 1) t = 0.5f * t * (1.0f + erff(t * 0.70710678118654752f));
                if (EPI == 2) t += R[(size_t)(m0 + e) * N + n];
                Cm[(size_t)(m0 + e) * N + n] = (OutT)t;
            }
        }
    }
}

// ---------------------------------------------------------------------------
// Flash attention (fp32): one block per (b,h,qtile of 64). Writes y as bf16.
// ---------------------------------------------------------------------------
__global__ __launch_bounds__(256) void attn_flash(
    const float* __restrict__ qkv, const int* __restrict__ amask,
    __bf16* __restrict__ ybuf, float* __restrict__ mbuf, float* __restrict__ lbuf)
{
    constexpr int PW = 68;
    __shared__ __align__(16) float Qt[64][PW];   // Qt[d][q]
    __shared__ __align__(16) float KP[64][PW];   // Kt[d][k], then Ps[q][k]
    __shared__ __align__(16) float Vs[64][PW];   // Vs[k][d]

    int blk = blockIdx.x;
    int qt = blk & 15;
    int h  = (blk >> 4) & 15;
    int b  = blk >> 8;
    int q0 = qt * 64;

    int tid = threadIdx.x;
    int tx = tid & 15, ty = tid >> 4;
    int lr = tid >> 4;
    const size_t bbase = (size_t)b * Tc * 3 * Cc;

    #pragma unroll
    for (int p = 0; p < 4; p++) {
        int r = p * 16 + lr;
        float4 v = *(const float4*)(qkv + bbase + (size_t)(q0 + r) * 3*Cc + h*64 + tx*4);
        Qt[tx*4+0][r] = v.x; Qt[tx*4+1][r] = v.y;
        Qt[tx*4+2][r] = v.z; Qt[tx*4+3][r] = v.w;
    }

    float m_i[4], l_i[4], O[4][4];
    #pragma unroll
    for (int i = 0; i < 4; i++) {
        m_i[i] = -INFINITY; l_i[i] = 0.f;
        #pragma unroll
        for (int j = 0; j < 4; j++) O[i][j] = 0.f;
    }

    for (int kt = 0; kt <= qt; kt++) {
        int k0 = kt * 64;
        __syncthreads();
        #pragma unroll
        for (int p = 0; p < 4; p++) {
            int r = p * 16 + lr;
            float4 k4 = *(const float4*)(qkv + bbase + (size_t)(k0 + r)*3*Cc + Cc + h*64 + tx*4);
            KP[tx*4+0][r] = k4.x; KP[tx*4+1][r] = k4.y;
            KP[tx*4+2][r] = k4.z; KP[tx*4+3][r] = k4.w;
            float4 v4 = *(const float4*)(qkv + bbase + (size_t)(k0 + r)*3*Cc + 2*Cc + h*64 + tx*4);
            *(float4*)&Vs[r][tx*4] = v4;
        }
        __syncthreads();

        float acc[4][4] = {};
        #pragma unroll 8
        for (int d = 0; d < 64; d++) {
            float4 q4 = *(const float4*)&Qt[d][ty*4];
            float4 k4 = *(const float4*)&KP[d][tx*4];
            const float qa[4] = {q4.x, q4.y, q4.z, q4.w};
            const float ka[4] = {k4.x, k4.y, k4.z, k4.w};
            #pragma unroll
            for (int i = 0; i < 4; i++)
                #pragma unroll
                for (int j = 0; j < 4; j++)
                    acc[i][j] += qa[i] * ka[j];
        }

        int am[4];
        #pragma unroll
        for (int j = 0; j < 4; j++) am[j] = amask[b*Tc + k0 + tx*4 + j];

        __syncthreads();

        float pv[4][4];
        float alpha[4];
        #pragma unroll
        for (int i = 0; i < 4; i++) {
            int qg = q0 + ty*4 + i;
            float s[4];
            float rmax = -INFINITY;
            #pragma unroll
            for (int j = 0; j < 4; j++) {
                int kg = k0 + tx*4 + j;
                s[j] = (kg <= qg && am[j] != 0) ? acc[i][j] * 0.125f : -INFINITY;
                rmax = fmaxf(rmax, s[j]);
            }
            #pragma unroll
            for (int off = 8; off; off >>= 1)
                rmax = fmaxf(rmax, __shfl_xor(rmax, off, 16));
            float mnew = fmaxf(m_i[i], rmax);
            alpha[i] = (m_i[i] == -INFINITY) ? 0.f : __expf(m_i[i] - mnew);
            float rsum = 0.f;
            #pragma unroll
            for (int j = 0; j < 4; j++) {
                pv[i][j] = (s[j] == -INFINITY) ? 0.f : __expf(s[j] - mnew);
                rsum += pv[i][j];
            }
            #pragma unroll
            for (int off = 8; off; off >>= 1)
                rsum += __shfl_xor(rsum, off, 16);
            l_i[i] = alpha[i] * l_i[i] + rsum;
            m_i[i] = mnew;
            *(float4*)&KP[ty*4+i][tx*4] = make_float4(pv[i][0], pv[i][1], pv[i][2], pv[i][3]);
            #pragma unroll
            for (int j = 0; j < 4; j++) O[i][j] *= alpha[i];
        }
        __syncthreads();

        #pragma unroll 4
        for (int kc = 0; kc < 16; kc++) {
            float pa[4][4], va[4][4];
            #pragma unroll
            for (int i = 0; i < 4; i++) {
                float4 t4 = *(const float4*)&KP[ty*4+i][kc*4];
                pa[i][0] = t4.x; pa[i][1] = t4.y; pa[i][2] = t4.z; pa[i][3] = t4.w;
            }
            #pragma unroll
            for (int kk = 0; kk < 4; kk++) {
                float4 t4 = *(const float4*)&Vs[kc*4+kk][tx*4];
                va[kk][0] = t4.x; va[kk][1] = t4.y; va[kk][2] = t4.z; va[kk][3] = t4.w;
            }
            #pragma unroll
            for (int i = 0; i < 4; i++)
                #pragma unroll
                for (int kk = 0; kk < 4; kk++)
                    #pragma unroll
                    for (int jd = 0; jd < 4; jd++)
                        O[i][jd] += pa[i][kk] * va[kk][jd];
        }
    }

    #pragma unroll
    for (int i = 0; i < 4; i++) {
        int qg = q0 + ty*4 + i;
        float invl = (l_i[i] > 0.f) ? 1.f / l_i[i] : 0.f;
        bf16x4 o = { (__bf16)(O[i][0]*invl), (__bf16)(O[i][1]*invl),
                     (__bf16)(O[i][2]*invl), (__bf16)(O[i][3]*invl) };
        *(bf16x4*)(ybuf + (size_t)(b*Tc + qg) * Cc + h*64 + tx*4) = o;
        if (tx == 0) {
            mbuf[(size_t)(b*Hc + h)*Tc + qg] = m_i[i];
            lbuf[(size_t)(b*Hc + h)*Tc + qg] = l_i[i];
        }
    }
}

// ---------------------------------------------------------------------------
// imp pass, tiled (fp32): one block per (b,h,ktile of 64). atomicAdd into impb.
// ---------------------------------------------------------------------------
__global__ __launch_bounds__(256) void imp_flash(
    const float* __restrict__ qkv, const int* __restrict__ amask,
    const float* __restrict__ mbuf, const float* __restrict__ lbuf,
    float* __restrict__ impbuf)
{
    constexpr int PW = 68;
    __shared__ __align__(16) float Kt[64][PW];
    __shared__ __align__(16) float Qt[64][PW];
    __shared__ float mls[64], rls[64];

    int blk = blockIdx.x;
    int ktile = blk & 15;
    int h = (blk >> 4) & 15;
    int b = blk >> 8;
    int k0 = ktile * 64;
    int tid = threadIdx.x, tx = tid & 15, ty = tid >> 4;
    int lr = tid >> 4;
    const size_t bbase = (size_t)b * Tc * 3 * Cc;

    #pragma unroll
    for (int p = 0; p < 4; p++) {
        int r = p * 16 + lr;
        float4 k4 = *(const float4*)(qkv + bbase + (size_t)(k0 + r)*3*Cc + Cc + h*64 + tx*4);
        Kt[tx*4+0][r] = k4.x; Kt[tx*4+1][r] = k4.y;
        Kt[tx*4+2][r] = k4.z; Kt[tx*4+3][r] = k4.w;
    }
    int am[4];
    #pragma unroll
    for (int i = 0; i < 4; i++) am[i] = amask[b*Tc + k0 + ty*4 + i];

    float sums[4] = {0.f, 0.f, 0.f, 0.f};

    for (int qt = ktile; qt < 16; qt++) {
        int q0 = qt * 64;
        __syncthreads();
        #pragma unroll
        for (int p = 0; p < 4; p++) {
            int r = p * 16 + lr;
            float4 q4 = *(const float4*)(qkv + bbase + (size_t)(q0 + r)*3*Cc + h*64 + tx*4);
            Qt[tx*4+0][r] = q4.x; Qt[tx*4+1][r] = q4.y;
            Qt[tx*4+2][r] = q4.z; Qt[tx*4+3][r] = q4.w;
        }
        if (tid < 64) {
            float l = lbuf[(size_t)(b*Hc + h)*Tc + q0 + tid];
            mls[tid] = mbuf[(size_t)(b*Hc + h)*Tc + q0 + tid];
            rls[tid] = (l > 0.f) ? 1.f / l : 0.f;
        }
        __syncthreads();

        float acc[4][4] = {};
        #pragma unroll 8
        for (int d = 0; d < 64; d++) {
            float4 k4 = *(const float4*)&Kt[d][ty*4];
            float4 q4 = *(const float4*)&Qt[d][tx*4];
            const float ka[4] = {k4.x, k4.y, k4.z, k4.w};
            const float qa[4] = {q4.x, q4.y, q4.z, q4.w};
            #pragma unroll
            for (int i = 0; i < 4; i++)
                #pragma unroll
                for (int j = 0; j < 4; j++)
                    acc[i][j] += ka[i] * qa[j];
        }

        #pragma unroll
        for (int i = 0; i < 4; i++) {
            if (!am[i]) continue;
            int kg = k0 + ty*4 + i;
            #pragma unroll
            for (int j = 0; j < 4; j++) {
                int qg = q0 + tx*4 + j;
                float rl = rls[tx*4 + j];
                if (kg <= qg && rl > 0.f)
                    sums[i] += __expf(acc[i][j] * 0.125f - mls[tx*4 + j]) * rl;
            }
        }
    }

    #pragma unroll
    for (int i = 0; i < 4; i++) {
        float s = sums[i];
        #pragma unroll
        for (int off = 8; off; off >>= 1) s += __shfl_xor(s, off, 16);
        if (tx == 0) atomicAdd(&impbuf[b*Tc + k0 + ty*4 + i], s);
    }
}

// ---------------------------------------------------------------------------
// Finalize: scale raw sums by 1/H and pos_norm, global max, sinks, mask.
// ---------------------------------------------------------------------------
__global__ __launch_bounds__(1024) void finalize_kernel(
    const float* __restrict__ impbuf, const int* __restrict__ amask,
    const float* __restrict__ thr, float* __restrict__ out_mask,
    float* __restrict__ out_imp)
{
    __shared__ float red[16];
    int tid = threadIdx.x;
    float vloc[4];
    float gmax = -INFINITY;
    #pragma unroll
    for (int it = 0; it < 4; it++) {
        int i = tid + it * 1024;
        int tt = i % Tc;
        float posn = (float)(Tc - tt) / (float)Tc;
        float v = impbuf[i] * (1.0f / Hc) / (posn + 1e-8f);
        vloc[it] = v;
        gmax = fmaxf(gmax, v);
    }
    for (int off = 32; off; off >>= 1) gmax = fmaxf(gmax, __shfl_down(gmax, off, 64));
    if ((tid & 63) == 0) red[tid >> 6] = gmax;
    __syncthreads();
    float gm = red[0];
    #pragma unroll
    for (int i = 1; i < 16; i++) gm = fmaxf(gm, red[i]);

    float t = thr[0];
    #pragma unroll
    for (int it = 0; it < 4; it++) {
        int i = tid + it * 1024;
        int tt = i % Tc;
        float v = vloc[it];
        if (tt < SINKc) v = gm + 1.0f;
        float mk = (v >= t) ? 1.f : 0.f;
        if (tt < SINKc) mk = 1.f;
        mk *= (float)amask[i];
        out_imp[i]  = v;
        out_mask[i] = mk;
    }
}

// ---------------------------------------------------------------------------
extern "C" void kernel_launch(void* const* d_in, const int* in_sizes, int n_in,
                              void* d_out, int out_size, void* d_ws, size_t ws_size,
                              hipStream_t stream)
{
    const float* x      = (const float*)d_in[0];
    const int*   amask  = (const int*)  d_in[1];
    const float* W_attn = (const float*)d_in[2];
    const float* b_attn = (const float*)d_in[3];
    const float* W_proj = (const float*)d_in[4];
    const float* b_proj = (const float*)d_in[5];
    const float* ln1w   = (const float*)d_in[6];
    const float* ln1b   = (const float*)d_in[7];
    const float* ln2w   = (const float*)d_in[8];
    const float* ln2b   = (const float*)d_in[9];
    const float* W_fc   = (const float*)d_in[10];
    const float* b_fc   = (const float*)d_in[11];
    const float* W_fc2  = (const float*)d_in[12];
    const float* b_fc2  = (const float*)d_in[13];
    const float* thr    = (const float*)d_in[14];

    float* out      = (float*)d_out;                 // (B,T,C)
    float* out_mask = out + (size_t)Bc * Tc * Cc;    // (B,T)
    float* out_imp  = out_mask + (size_t)Bc * Tc;    // (B,T)

    // Workspace layout (element offsets; all 16B-aligned)
    char* wsb = (char*)d_ws;
    float*  qkv  = (float*)wsb;                         // 12.58M f32 = 50,331,648 B
    __bf16* hbf  = (__bf16*)(wsb + 50331648);           // 4M bf16   =  8,388,608 B
    __bf16* ybf  = (__bf16*)(wsb + 58720256);           // 4M bf16   =  8,388,608 B
    __bf16* fcbf = (__bf16*)(wsb + 67108864);           // 16M bf16  = 33,554,432 B
    __bf16* WaT  = (__bf16*)(wsb + 100663296);          // 3M bf16   =  6,291,456 B
    __bf16* WpT  = (__bf16*)(wsb + 106954752);          // 1M bf16   =  2,097,152 B
    __bf16* WfT  = (__bf16*)(wsb + 109051904);          // 4M bf16   =  8,388,608 B
    __bf16* Wf2T = (__bf16*)(wsb + 117440512);          // 4M bf16   =  8,388,608 B
    float*  mbuf = (float*)(wsb + 125829120);           // 64K f32
    float*  lbuf = (float*)(wsb + 126091264);           // 64K f32
    float*  impb = (float*)(wsb + 126353408);           // 4K f32

    const int M = Bc * Tc;   // 4096

    // Weight transpose+convert: W[K][N] -> Wt[N][K] bf16
    transpose_bf16<<<dim3(3*Cc/32, Cc/32), 256, 0, stream>>>(W_attn, WaT, Cc, 3*Cc);
    transpose_bf16<<<dim3(Cc/32,   Cc/32), 256, 0, stream>>>(W_proj, WpT, Cc, Cc);
    transpose_bf16<<<dim3(4*Cc/32, Cc/32), 256, 0, stream>>>(W_fc,   WfT, Cc, 4*Cc);
    transpose_bf16<<<dim3(Cc/32, 4*Cc/32), 256, 0, stream>>>(W_fc2,  Wf2T, 4*Cc, Cc);

    // h = ln1(x) -> bf16
    ln_kernel<<<M, 256, 0, stream>>>(x, ln1w, ln1b, hbf);
    // qkv = h @ W_attn + b_attn  (fp32 out for attention numerics)
    gemm_bf16<0, float><<<dim3(3*Cc/128, M/128), 256, 0, stream>>>(
        hbf, WaT, b_attn, nullptr, qkv, M, 3*Cc, Cc);
    // zero the imp accumulator
    hipMemsetAsync(impb, 0, (size_t)Bc * Tc * sizeof(float), stream);
    // attention -> y (bf16), (m,l)
    attn_flash<<<Bc * Hc * (Tc / 64), 256, 0, stream>>>(qkv, amask, ybf, mbuf, lbuf);
    // x2 = x + y @ W_proj + b_proj   (into d_out, fp32)
    gemm_bf16<2, float><<<dim3(Cc/128, M/128), 256, 0, stream>>>(
        ybf, WpT, b_proj, x, out, M, Cc, Cc);
    // imp accumulation (needs mbuf/lbuf)
    imp_flash<<<Bc * Hc * (Tc / 64), 256, 0, stream>>>(qkv, amask, mbuf, lbuf, impb);
    // m = ln2(x2) -> bf16 (reuse hbf)
    ln_kernel<<<M, 256, 0, stream>>>(out, ln2w, ln2b, hbf);
    // fc = gelu(m @ W_fc + b_fc) -> bf16
    gemm_bf16<1, __bf16><<<dim3(4*Cc/128, M/128), 256, 0, stream>>>(
        hbf, WfT, b_fc, nullptr, fcbf, M, 4*Cc, Cc);
    // out = x2 + fc @ W_fc2 + b_fc2   (in-place residual from d_out)
    gemm_bf16<2, float><<<dim3(Cc/128, M/128), 256, 0, stream>>>(
        fcbf, Wf2T, b_fc2, out, out, M, Cc, 4*Cc);
    // mask & imp outputs
    finalize_kernel<<<1, 1024, 0, stream>>>(impb, amask, thr, out_mask, out_imp);
}

// Round 4
// 464.015 us; speedup vs baseline: 11.3477x; 1.6978x over previous
//
#include <hip/hip_runtime.h>
#include <math.h>

// Problem constants (match reference)
constexpr int Bc = 4, Tc = 1024, Cc = 1024, Hc = 16, Dc = 64, SINKc = 4;
constexpr float EPS_LN = 1e-5f;

typedef __bf16 bf16x4 __attribute__((ext_vector_type(4)));
typedef __bf16 bf16x8 __attribute__((ext_vector_type(8)));
typedef float  f32x4  __attribute__((ext_vector_type(4)));

// ---------------------------------------------------------------------------
// Transpose + fp32->bf16 convert: W[K][N] -> Wt[N][K]. 32x32 tiles.
// ---------------------------------------------------------------------------
__global__ __launch_bounds__(256) void transpose_bf16(
    const float* __restrict__ W, __bf16* __restrict__ Wt, int K, int N)
{
    __shared__ float S[32][33];
    int n0 = blockIdx.x * 32, k0 = blockIdx.y * 32;
    int t = threadIdx.x;
    int r = t >> 3, c4 = (t & 7) * 4;
    float4 v = *(const float4*)(W + (size_t)(k0 + r) * N + n0 + c4);
    S[r][c4+0] = v.x; S[r][c4+1] = v.y; S[r][c4+2] = v.z; S[r][c4+3] = v.w;
    __syncthreads();
    bf16x4 o = { (__bf16)S[c4+0][r], (__bf16)S[c4+1][r],
                 (__bf16)S[c4+2][r], (__bf16)S[c4+3][r] };
    *(bf16x4*)(Wt + (size_t)(n0 + r) * K + k0 + c4) = o;
}

// ---------------------------------------------------------------------------
// LayerNorm: one 256-thread block per row of C=1024. Writes bf16.
// ---------------------------------------------------------------------------
__global__ __launch_bounds__(256) void ln_kernel(
    const float* __restrict__ x, const float* __restrict__ w,
    const float* __restrict__ bsh, __bf16* __restrict__ outp)
{
    int row = blockIdx.x;
    const float* xr = x + (size_t)row * Cc;
    int tid = threadIdx.x;

    float4 xl = reinterpret_cast<const float4*>(xr)[tid];
    float s  = xl.x + xl.y + xl.z + xl.w;
    float s2 = xl.x*xl.x + xl.y*xl.y + xl.z*xl.z + xl.w*xl.w;
    for (int off = 32; off; off >>= 1) {
        s  += __shfl_down(s,  off, 64);
        s2 += __shfl_down(s2, off, 64);
    }
    __shared__ float r1[4], r2[4];
    if ((tid & 63) == 0) { r1[tid >> 6] = s; r2[tid >> 6] = s2; }
    __syncthreads();
    float mu  = (r1[0]+r1[1]+r1[2]+r1[3]) * (1.0f / Cc);
    float var = (r2[0]+r2[1]+r2[2]+r2[3]) * (1.0f / Cc) - mu*mu;
    float rstd = rsqrtf(var + EPS_LN);

    float4 wl = reinterpret_cast<const float4*>(w)[tid];
    float4 bl = reinterpret_cast<const float4*>(bsh)[tid];
    bf16x4 o = { (__bf16)((xl.x - mu) * rstd * wl.x + bl.x),
                 (__bf16)((xl.y - mu) * rstd * wl.y + bl.y),
                 (__bf16)((xl.z - mu) * rstd * wl.z + bl.z),
                 (__bf16)((xl.w - mu) * rstd * wl.w + bl.w) };
    *(bf16x4*)(outp + (size_t)row * Cc + tid * 4) = o;
}

// ---------------------------------------------------------------------------
// bf16 MFMA GEMM: C[M][N] = A[M][K] @ Bt[N][K]^T + bias[N]
//   EPI=0: none   EPI=1: exact GELU   EPI=2: + R[m][n] (fp32 residual)
// 128x128 tile, BK=32, 256 threads (4 waves 2x2, each 64x64 via 4x4 MFMA
// tiles of 16x16x32). global_load_lds width=16 staging; LDS chunk index
// XOR-swizzled with (row>>1)&3 so fragment ds_read_b128 is 2-way (free).
// ---------------------------------------------------------------------------
template <int EPI, typename OutT>
__global__ __launch_bounds__(256) void gemm_bf16(
    const __bf16* __restrict__ A, const __bf16* __restrict__ Bt,
    const float* __restrict__ bias, const float* R,
    OutT* Cm, int M, int N, int K)
{
    __shared__ __bf16 As[128 * 32];
    __shared__ __bf16 Bs[128 * 32];

    const int tid  = threadIdx.x;
    const int wave = tid >> 6, lane = tid & 63;
    const int wm = wave >> 1, wn = wave & 1;
    const int lr = lane & 15, lc = lane >> 4;
    const int bx = blockIdx.x, by = blockIdx.y;

    f32x4 acc[4][4] = {};

    const int srow = lane >> 2;
    const int cphys = lane & 3;

    for (int k0 = 0; k0 < K; k0 += 32) {
        __syncthreads();
        #pragma unroll
        for (int t = 0; t < 2; t++) {
            int idx  = wave * 2 + t;
            int rloc = idx * 16 + srow;
            int clog = (cphys - (rloc >> 1)) & 3;
            const __bf16* ga = A  + (size_t)(by * 128 + rloc) * K + k0 + clog * 8;
            const __bf16* gb = Bt + (size_t)(bx * 128 + rloc) * K + k0 + clog * 8;
            __builtin_amdgcn_global_load_lds(
                (const __attribute__((address_space(1))) void*)ga,
                (__attribute__((address_space(3))) void*)(As + idx * 512), 16, 0, 0);
            __builtin_amdgcn_global_load_lds(
                (const __attribute__((address_space(1))) void*)gb,
                (__attribute__((address_space(3))) void*)(Bs + idx * 512), 16, 0, 0);
        }
        __syncthreads();

        bf16x8 af[4], bfr[4];
        #pragma unroll
        for (int i = 0; i < 4; i++) {
            int ra = wm * 64 + i * 16 + lr;
            int ca = (lc + (ra >> 1)) & 3;
            af[i]  = *(const bf16x8*)(As + ra * 32 + ca * 8);
            int rb = wn * 64 + i * 16 + lr;
            int cb = (lc + (rb >> 1)) & 3;
            bfr[i] = *(const bf16x8*)(Bs + rb * 32 + cb * 8);
        }
        #pragma unroll
        for (int i = 0; i < 4; i++)
            #pragma unroll
            for (int j = 0; j < 4; j++)
                acc[i][j] = __builtin_amdgcn_mfma_f32_16x16x32_bf16(
                    af[i], bfr[j], acc[i][j], 0, 0, 0);
    }

    #pragma unroll
    for (int j = 0; j < 4; j++) {
        int n = bx * 128 + wn * 64 + j * 16 + lr;
        float bv = bias[n];
        #pragma unroll
        for (int i = 0; i < 4; i++) {
            int m0 = by * 128 + wm * 64 + i * 16 + lc * 4;
            #pragma unroll
            for (int e = 0; e < 4; e++) {
                float t = acc[i][j][e] + bv;
                if (EPI == 1) t = 0.5f * t * (1.0f + erff(t * 0.70710678118654752f));
                if (EPI == 2) t += R[(size_t)(m0 + e) * N + n];
                Cm[(size_t)(m0 + e) * N + n] = (OutT)t;
            }
        }
    }
}

// ---------------------------------------------------------------------------
// MFMA flash attention: one block per (b,h,qtile of 64). 4 waves; wave w owns
// q rows w*16..w*16+16. Q A-frags direct global->reg (once). K staged via
// swizzled global_load_lds; V transposed into LDS; P round-trips via LDS
// (C-layout -> A-layout). Online softmax state per lane-row (quad*4+e).
// qt permuted (long blocks first, rotated by h+b) for CU load balance.
// ---------------------------------------------------------------------------
__global__ __launch_bounds__(256, 3) void attn_mfma(
    const __bf16* __restrict__ qkv, const int* __restrict__ amask,
    __bf16* __restrict__ ybuf, float* __restrict__ mbuf, float* __restrict__ lbuf)
{
    __shared__ __bf16 Kb[2][64 * 32];               // swizzled halves, 8 KB
    __shared__ __align__(16) __bf16 Vt[64][72];     // V^T [d][k], 9216 B
    __shared__ __align__(16) __bf16 Ps[64][72];     // P   [q][k], 9216 B

    int blk = blockIdx.x;
    int idx = blk & 15, h = (blk >> 4) & 15, b = blk >> 8;
    int idx2 = (idx + h + b) & 15;
    int p2 = idx2 >> 1;
    int qt = (idx2 & 1) ? p2 : (15 - p2);           // descending-ish work
    int q0 = qt * 64;

    int tid = threadIdx.x, wave = tid >> 6, lane = tid & 63;
    int quad = lane >> 4, l15 = lane & 15;
    const int srow = lane >> 2, cphys = lane & 3;
    const size_t RS = 3 * Cc;                       // qkv row stride (elems)
    const size_t bT = (size_t)b * Tc;

    // Q A-frags: rows wave*16 + l15, k = quad*8 (+32 for half 1)
    bf16x8 qf[2];
    {
        const __bf16* qrow = qkv + (bT + q0 + wave * 16 + l15) * RS + h * 64 + quad * 8;
        qf[0] = *(const bf16x8*)qrow;
        qf[1] = *(const bf16x8*)(qrow + 32);
    }

    float m_i[4], l_i[4];
    f32x4 Oacc[4] = {};
    #pragma unroll
    for (int e = 0; e < 4; e++) { m_i[e] = -INFINITY; l_i[e] = 0.f; }

    for (int kt = 0; kt <= qt; kt++) {
        int k0 = kt * 64;
        __syncthreads();                            // prev Kb/Vt/Ps reads done

        // Stage K tile (wave w loads rows w*16..+16, both halves, swizzled)
        #pragma unroll
        for (int c = 0; c < 2; c++) {
            int rloc = wave * 16 + srow;
            int clog = (cphys - (rloc >> 1)) & 3;
            const __bf16* g = qkv + (bT + k0 + rloc) * RS + Cc + h * 64 + c * 32 + clog * 8;
            __builtin_amdgcn_global_load_lds(
                (const __attribute__((address_space(1))) void*)g,
                (__attribute__((address_space(3))) void*)(&Kb[c][wave * 512]), 16, 0, 0);
        }
        // Stage V transposed: thread (wave,lane) covers k=lane, d=wave*16..+16
        {
            int kk = lane, dbase = wave * 16;
            const __bf16* vrow = qkv + (bT + k0 + kk) * RS + 2 * Cc + h * 64 + dbase;
            bf16x8 v0 = *(const bf16x8*)vrow;
            bf16x8 v1 = *(const bf16x8*)(vrow + 8);
            #pragma unroll
            for (int j = 0; j < 8; j++) Vt[dbase + j][kk] = v0[j];
            #pragma unroll
            for (int j = 0; j < 8; j++) Vt[dbase + 8 + j][kk] = v1[j];
        }
        int am4[4];
        #pragma unroll
        for (int j = 0; j < 4; j++) am4[j] = amask[bT + k0 + j * 16 + l15];
        __syncthreads();

        // S = Q K^T : C col = k (j*16+l15), row = q (quad*4+e)
        f32x4 Sacc[4] = {};
        #pragma unroll
        for (int c = 0; c < 2; c++)
            #pragma unroll
            for (int j = 0; j < 4; j++) {
                int rb = j * 16 + l15;
                int cb = (quad + (rb >> 1)) & 3;
                bf16x8 kf = *(const bf16x8*)(&Kb[c][rb * 32 + cb * 8]);
                Sacc[j] = __builtin_amdgcn_mfma_f32_16x16x32_bf16(qf[c], kf, Sacc[j], 0, 0, 0);
            }

        // Online softmax + write P (bf16) to LDS
        #pragma unroll
        for (int e = 0; e < 4; e++) {
            int qg = q0 + wave * 16 + quad * 4 + e;
            float sv[4], rmax = -INFINITY;
            #pragma unroll
            for (int j = 0; j < 4; j++) {
                int kg = k0 + j * 16 + l15;
                sv[j] = (kg <= qg && am4[j] != 0) ? Sacc[j][e] * 0.125f : -INFINITY;
                rmax = fmaxf(rmax, sv[j]);
            }
            #pragma unroll
            for (int off = 8; off; off >>= 1)
                rmax = fmaxf(rmax, __shfl_xor(rmax, off, 64));
            float mnew = fmaxf(m_i[e], rmax);
            float alpha = (m_i[e] == -INFINITY) ? 0.f : __expf(m_i[e] - mnew);
            float rsum = 0.f, pj[4];
            #pragma unroll
            for (int j = 0; j < 4; j++) {
                pj[j] = (sv[j] == -INFINITY) ? 0.f : __expf(sv[j] - mnew);
                rsum += pj[j];
            }
            #pragma unroll
            for (int off = 8; off; off >>= 1)
                rsum += __shfl_xor(rsum, off, 64);
            l_i[e] = alpha * l_i[e] + rsum;
            m_i[e] = mnew;
            #pragma unroll
            for (int j2 = 0; j2 < 4; j2++) Oacc[j2][e] *= alpha;
            #pragma unroll
            for (int j = 0; j < 4; j++)
                Ps[wave * 16 + quad * 4 + e][j * 16 + l15] = (__bf16)pj[j];
        }
        __syncthreads();                            // P visible

        // O += P V : A = Ps rows q, B = Vt rows d
        #pragma unroll
        for (int c2 = 0; c2 < 2; c2++) {
            bf16x8 pa = *(const bf16x8*)(&Ps[wave * 16 + l15][quad * 8 + c2 * 32]);
            #pragma unroll
            for (int j2 = 0; j2 < 4; j2++) {
                bf16x8 vb = *(const bf16x8*)(&Vt[j2 * 16 + l15][quad * 8 + c2 * 32]);
                Oacc[j2] = __builtin_amdgcn_mfma_f32_16x16x32_bf16(pa, vb, Oacc[j2], 0, 0, 0);
            }
        }
    }

    // Epilogue: y = O/l (bf16), save m,l
    #pragma unroll
    for (int e = 0; e < 4; e++) {
        int qg = q0 + wave * 16 + quad * 4 + e;
        float invl = (l_i[e] > 0.f) ? 1.f / l_i[e] : 0.f;
        #pragma unroll
        for (int j2 = 0; j2 < 4; j2++)
            ybuf[(bT + qg) * Cc + h * 64 + j2 * 16 + l15] = (__bf16)(Oacc[j2][e] * invl);
        if (l15 == 0) {
            mbuf[(size_t)(b * Hc + h) * Tc + qg] = m_i[e];
            lbuf[(size_t)(b * Hc + h) * Tc + qg] = l_i[e];
        }
    }
}

// ---------------------------------------------------------------------------
// MFMA imp pass: one block per (b,h,ktile of 64). S^T = K Q^T via MFMA
// (A=K rows -> C row=k, B=Q rows -> C col=q); accumulate exp(s-m_q)/l_q
// over q>=k; one atomicAdd per k row at the end. kt permuted for balance.
// ---------------------------------------------------------------------------
__global__ __launch_bounds__(256, 4) void imp_mfma(
    const __bf16* __restrict__ qkv, const int* __restrict__ amask,
    const float* __restrict__ mbuf, const float* __restrict__ lbuf,
    float* __restrict__ impbuf)
{
    __shared__ __bf16 Qb[2][64 * 32];               // swizzled halves, 8 KB
    __shared__ float mls[64], rls[64];

    int blk = blockIdx.x;
    int idx = blk & 15, h = (blk >> 4) & 15, b = blk >> 8;
    int idx2 = (idx + h + b) & 15;
    int p2 = idx2 >> 1;
    int kt = (idx2 & 1) ? (15 - p2) : p2;           // descending-ish work
    int k0 = kt * 64;

    int tid = threadIdx.x, wave = tid >> 6, lane = tid & 63;
    int quad = lane >> 4, l15 = lane & 15;
    const int srow = lane >> 2, cphys = lane & 3;
    const size_t RS = 3 * Cc;
    const size_t bT = (size_t)b * Tc;
    const size_t mlrow = (size_t)(b * Hc + h) * Tc;

    // K A-frags direct: rows wave*16 + l15
    bf16x8 kf[2];
    {
        const __bf16* krow = qkv + (bT + k0 + wave * 16 + l15) * RS + Cc + h * 64 + quad * 8;
        kf[0] = *(const bf16x8*)krow;
        kf[1] = *(const bf16x8*)(krow + 32);
    }
    int amk[4];
    #pragma unroll
    for (int e = 0; e < 4; e++) amk[e] = amask[bT + k0 + wave * 16 + quad * 4 + e];

    float sums[4] = {0.f, 0.f, 0.f, 0.f};

    for (int qt = kt; qt < 16; qt++) {
        int q0 = qt * 64;
        __syncthreads();
        #pragma unroll
        for (int c = 0; c < 2; c++) {
            int rloc = wave * 16 + srow;
            int clog = (cphys - (rloc >> 1)) & 3;
            const __bf16* g = qkv + (bT + q0 + rloc) * RS + h * 64 + c * 32 + clog * 8;
            __builtin_amdgcn_global_load_lds(
                (const __attribute__((address_space(1))) void*)g,
                (__attribute__((address_space(3))) void*)(&Qb[c][wave * 512]), 16, 0, 0);
        }
        if (tid < 64) {
            float l = lbuf[mlrow + q0 + tid];
            mls[tid] = mbuf[mlrow + q0 + tid];
            rls[tid] = (l > 0.f) ? 1.f / l : 0.f;
        }
        __syncthreads();

        f32x4 Sacc[4] = {};
        #pragma unroll
        for (int c = 0; c < 2; c++)
            #pragma unroll
            for (int j = 0; j < 4; j++) {
                int rb = j * 16 + l15;
                int cb = (quad + (rb >> 1)) & 3;
                bf16x8 qb = *(const bf16x8*)(&Qb[c][rb * 32 + cb * 8]);
                Sacc[j] = __builtin_amdgcn_mfma_f32_16x16x32_bf16(kf[c], qb, Sacc[j], 0, 0, 0);
            }

        #pragma unroll
        for (int j = 0; j < 4; j++) {
            int qg = q0 + j * 16 + l15;
            float ml = mls[j * 16 + l15], rl = rls[j * 16 + l15];
            #pragma unroll
            for (int e = 0; e < 4; e++) {
                int kg = k0 + wave * 16 + quad * 4 + e;
                if (kg <= qg && amk[e] != 0 && rl > 0.f)
                    sums[e] += __expf(Sacc[j][e] * 0.125f - ml) * rl;
            }
        }
    }

    #pragma unroll
    for (int e = 0; e < 4; e++) {
        float s = sums[e];
        #pragma unroll
        for (int off = 8; off; off >>= 1) s += __shfl_xor(s, off, 64);
        if (l15 == 0)
            atomicAdd(&impbuf[bT + k0 + wave * 16 + quad * 4 + e], s);
    }
}

// ---------------------------------------------------------------------------
// Finalize: scale raw sums by 1/H and pos_norm, global max, sinks, mask.
// ---------------------------------------------------------------------------
__global__ __launch_bounds__(1024) void finalize_kernel(
    const float* __restrict__ impbuf, const int* __restrict__ amask,
    const float* __restrict__ thr, float* __restrict__ out_mask,
    float* __restrict__ out_imp)
{
    __shared__ float red[16];
    int tid = threadIdx.x;
    float vloc[4];
    float gmax = -INFINITY;
    #pragma unroll
    for (int it = 0; it < 4; it++) {
        int i = tid + it * 1024;
        int tt = i % Tc;
        float posn = (float)(Tc - tt) / (float)Tc;
        float v = impbuf[i] * (1.0f / Hc) / (posn + 1e-8f);
        vloc[it] = v;
        gmax = fmaxf(gmax, v);
    }
    for (int off = 32; off; off >>= 1) gmax = fmaxf(gmax, __shfl_down(gmax, off, 64));
    if ((tid & 63) == 0) red[tid >> 6] = gmax;
    __syncthreads();
    float gm = red[0];
    #pragma unroll
    for (int i = 1; i < 16; i++) gm = fmaxf(gm, red[i]);

    float t = thr[0];
    #pragma unroll
    for (int it = 0; it < 4; it++) {
        int i = tid + it * 1024;
        int tt = i % Tc;
        float v = vloc[it];
        if (tt < SINKc) v = gm + 1.0f;
        float mk = (v >= t) ? 1.f : 0.f;
        if (tt < SINKc) mk = 1.f;
        mk *= (float)amask[i];
        out_imp[i]  = v;
        out_mask[i] = mk;
    }
}

// ---------------------------------------------------------------------------
extern "C" void kernel_launch(void* const* d_in, const int* in_sizes, int n_in,
                              void* d_out, int out_size, void* d_ws, size_t ws_size,
                              hipStream_t stream)
{
    const float* x      = (const float*)d_in[0];
    const int*   amask  = (const int*)  d_in[1];
    const float* W_attn = (const float*)d_in[2];
    const float* b_attn = (const float*)d_in[3];
    const float* W_proj = (const float*)d_in[4];
    const float* b_proj = (const float*)d_in[5];
    const float* ln1w   = (const float*)d_in[6];
    const float* ln1b   = (const float*)d_in[7];
    const float* ln2w   = (const float*)d_in[8];
    const float* ln2b   = (const float*)d_in[9];
    const float* W_fc   = (const float*)d_in[10];
    const float* b_fc   = (const float*)d_in[11];
    const float* W_fc2  = (const float*)d_in[12];
    const float* b_fc2  = (const float*)d_in[13];
    const float* thr    = (const float*)d_in[14];

    float* out      = (float*)d_out;                 // (B,T,C)
    float* out_mask = out + (size_t)Bc * Tc * Cc;    // (B,T)
    float* out_imp  = out_mask + (size_t)Bc * Tc;    // (B,T)

    // Workspace layout (byte offsets; all 16B-aligned)
    char* wsb = (char*)d_ws;
    __bf16* qkvbf = (__bf16*)wsb;                       // 12.58M bf16 = 25,165,824 B
    __bf16* hbf   = (__bf16*)(wsb + 25165824);          //  8,388,608 B
    __bf16* ybf   = (__bf16*)(wsb + 33554432);          //  8,388,608 B
    __bf16* fcbf  = (__bf16*)(wsb + 41943040);          // 33,554,432 B
    __bf16* WaT   = (__bf16*)(wsb + 75497472);          //  6,291,456 B
    __bf16* WpT   = (__bf16*)(wsb + 81788928);          //  2,097,152 B
    __bf16* WfT   = (__bf16*)(wsb + 83886080);          //  8,388,608 B
    __bf16* Wf2T  = (__bf16*)(wsb + 92274688);          //  8,388,608 B
    float*  mbuf  = (float*)(wsb + 100663296);          //    262,144 B
    float*  lbuf  = (float*)(wsb + 100925440);          //    262,144 B
    float*  impb  = (float*)(wsb + 101187584);          //     16,384 B

    const int M = Bc * Tc;   // 4096

    // Weight transpose+convert: W[K][N] -> Wt[N][K] bf16
    transpose_bf16<<<dim3(3*Cc/32, Cc/32), 256, 0, stream>>>(W_attn, WaT, Cc, 3*Cc);
    transpose_bf16<<<dim3(Cc/32,   Cc/32), 256, 0, stream>>>(W_proj, WpT, Cc, Cc);
    transpose_bf16<<<dim3(4*Cc/32, Cc/32), 256, 0, stream>>>(W_fc,   WfT, Cc, 4*Cc);
    transpose_bf16<<<dim3(Cc/32, 4*Cc/32), 256, 0, stream>>>(W_fc2,  Wf2T, 4*Cc, Cc);

    // h = ln1(x) -> bf16
    ln_kernel<<<M, 256, 0, stream>>>(x, ln1w, ln1b, hbf);
    // qkv = h @ W_attn + b_attn  -> bf16
    gemm_bf16<0, __bf16><<<dim3(3*Cc/128, M/128), 256, 0, stream>>>(
        hbf, WaT, b_attn, nullptr, qkvbf, M, 3*Cc, Cc);
    // zero the imp accumulator
    hipMemsetAsync(impb, 0, (size_t)Bc * Tc * sizeof(float), stream);
    // attention -> y (bf16), (m,l)
    attn_mfma<<<Bc * Hc * 16, 256, 0, stream>>>(qkvbf, amask, ybf, mbuf, lbuf);
    // x2 = x + y @ W_proj + b_proj   (into d_out, fp32)
    gemm_bf16<2, float><<<dim3(Cc/128, M/128), 256, 0, stream>>>(
        ybf, WpT, b_proj, x, out, M, Cc, Cc);
    // imp accumulation (needs mbuf/lbuf)
    imp_mfma<<<Bc * Hc * 16, 256, 0, stream>>>(qkvbf, amask, mbuf, lbuf, impb);
    // m = ln2(x2) -> bf16 (reuse hbf)
    ln_kernel<<<M, 256, 0, stream>>>(out, ln2w, ln2b, hbf);
    // fc = gelu(m @ W_fc + b_fc) -> bf16
    gemm_bf16<1, __bf16><<<dim3(4*Cc/128, M/128), 256, 0, stream>>>(
        hbf, WfT, b_fc, nullptr, fcbf, M, 4*Cc, Cc);
    // out = x2 + fc @ W_fc2 + b_fc2   (in-place residual from d_out)
    gemm_bf16<2, float><<<dim3(Cc/128, M/128), 256, 0, stream>>>(
        fcbf, Wf2T, b_fc2, out, out, M, Cc, 4*Cc);
    // mask & imp outputs
    finalize_kernel<<<1, 1024, 0, stream>>>(impb, amask, thr, out_mask, out_imp);
}

// Round 5
// 463.204 us; speedup vs baseline: 11.3676x; 1.0018x over previous
//
#include <hip/hip_runtime.h>
#include <math.h>

// Problem constants (match reference)
constexpr int Bc = 4, Tc = 1024, Cc = 1024, Hc = 16, Dc = 64, SINKc = 4;
constexpr float EPS_LN = 1e-5f;

typedef __bf16 bf16x4 __attribute__((ext_vector_type(4)));
typedef __bf16 bf16x8 __attribute__((ext_vector_type(8)));
typedef float  f32x4  __attribute__((ext_vector_type(4)));

// ---------------------------------------------------------------------------
// Transpose + fp32->bf16 convert: W[K][N] -> Wt[N][K]. 32x32 tiles.
// ---------------------------------------------------------------------------
__global__ __launch_bounds__(256) void transpose_bf16(
    const float* __restrict__ W, __bf16* __restrict__ Wt, int K, int N)
{
    __shared__ float S[32][33];
    int n0 = blockIdx.x * 32, k0 = blockIdx.y * 32;
    int t = threadIdx.x;
    int r = t >> 3, c4 = (t & 7) * 4;
    float4 v = *(const float4*)(W + (size_t)(k0 + r) * N + n0 + c4);
    S[r][c4+0] = v.x; S[r][c4+1] = v.y; S[r][c4+2] = v.z; S[r][c4+3] = v.w;
    __syncthreads();
    bf16x4 o = { (__bf16)S[c4+0][r], (__bf16)S[c4+1][r],
                 (__bf16)S[c4+2][r], (__bf16)S[c4+3][r] };
    *(bf16x4*)(Wt + (size_t)(n0 + r) * K + k0 + c4) = o;
}

// ---------------------------------------------------------------------------
// LayerNorm: one 256-thread block per row of C=1024. Writes bf16.
// ---------------------------------------------------------------------------
__global__ __launch_bounds__(256) void ln_kernel(
    const float* __restrict__ x, const float* __restrict__ w,
    const float* __restrict__ bsh, __bf16* __restrict__ outp)
{
    int row = blockIdx.x;
    const float* xr = x + (size_t)row * Cc;
    int tid = threadIdx.x;

    float4 xl = reinterpret_cast<const float4*>(xr)[tid];
    float s  = xl.x + xl.y + xl.z + xl.w;
    float s2 = xl.x*xl.x + xl.y*xl.y + xl.z*xl.z + xl.w*xl.w;
    for (int off = 32; off; off >>= 1) {
        s  += __shfl_down(s,  off, 64);
        s2 += __shfl_down(s2, off, 64);
    }
    __shared__ float r1[4], r2[4];
    if ((tid & 63) == 0) { r1[tid >> 6] = s; r2[tid >> 6] = s2; }
    __syncthreads();
    float mu  = (r1[0]+r1[1]+r1[2]+r1[3]) * (1.0f / Cc);
    float var = (r2[0]+r2[1]+r2[2]+r2[3]) * (1.0f / Cc) - mu*mu;
    float rstd = rsqrtf(var + EPS_LN);

    float4 wl = reinterpret_cast<const float4*>(w)[tid];
    float4 bl = reinterpret_cast<const float4*>(bsh)[tid];
    bf16x4 o = { (__bf16)((xl.x - mu) * rstd * wl.x + bl.x),
                 (__bf16)((xl.y - mu) * rstd * wl.y + bl.y),
                 (__bf16)((xl.z - mu) * rstd * wl.z + bl.z),
                 (__bf16)((xl.w - mu) * rstd * wl.w + bl.w) };
    *(bf16x4*)(outp + (size_t)row * Cc + tid * 4) = o;
}

// ---------------------------------------------------------------------------
// bf16 MFMA GEMM: C[M][N] = A[M][K] @ Bt[N][K]^T + bias[N]
//   EPI=0: none   EPI=1: exact GELU   EPI=2: + R[m][n] (fp32 residual)
// 128x128 tile, BK=32, 256 threads (4 waves 2x2). 1-D grid with XCD-aware
// supertile swizzle: blk%8 = XCD (round-robin dispatch), each XCD owns a
// contiguous rank range decoded GROUP_M=8-row-band column-first, so its
// 4 MB L2 holds the A band while B columns stream -> big FETCH cut.
// ---------------------------------------------------------------------------
template <int EPI, typename OutT>
__global__ __launch_bounds__(256) void gemm_bf16(
    const __bf16* __restrict__ A, const __bf16* __restrict__ Bt,
    const float* __restrict__ bias, const float* R,
    OutT* Cm, int M, int N, int K)
{
    __shared__ __bf16 As[128 * 32];
    __shared__ __bf16 Bs[128 * 32];

    const int tid  = threadIdx.x;
    const int wave = tid >> 6, lane = tid & 63;
    const int wm = wave >> 1, wn = wave & 1;
    const int lr = lane & 15, lc = lane >> 4;

    // --- XCD-aware supertile remap (bijection; perf-only) ---
    const int gx = N >> 7;                 // tiles along N
    const int nblk = gridDim.x;            // == gx * (M>>7), divisible by 8
    const int per = nblk >> 3;
    const int rank = (blockIdx.x & 7) * per + (blockIdx.x >> 3);
    const int GM = 8;                      // row-band height (divides M/128=32)
    const int grp = rank / (GM * gx);
    const int rem = rank % (GM * gx);
    const int by = grp * GM + (rem % GM);
    const int bx = rem / GM;

    f32x4 acc[4][4] = {};

    const int srow = lane >> 2;
    const int cphys = lane & 3;

    for (int k0 = 0; k0 < K; k0 += 32) {
        __syncthreads();
        #pragma unroll
        for (int t = 0; t < 2; t++) {
            int idx  = wave * 2 + t;
            int rloc = idx * 16 + srow;
            int clog = (cphys - (rloc >> 1)) & 3;
            const __bf16* ga = A  + (size_t)(by * 128 + rloc) * K + k0 + clog * 8;
            const __bf16* gb = Bt + (size_t)(bx * 128 + rloc) * K + k0 + clog * 8;
            __builtin_amdgcn_global_load_lds(
                (const __attribute__((address_space(1))) void*)ga,
                (__attribute__((address_space(3))) void*)(As + idx * 512), 16, 0, 0);
            __builtin_amdgcn_global_load_lds(
                (const __attribute__((address_space(1))) void*)gb,
                (__attribute__((address_space(3))) void*)(Bs + idx * 512), 16, 0, 0);
        }
        __syncthreads();

        bf16x8 af[4], bfr[4];
        #pragma unroll
        for (int i = 0; i < 4; i++) {
            int ra = wm * 64 + i * 16 + lr;
            int ca = (lc + (ra >> 1)) & 3;
            af[i]  = *(const bf16x8*)(As + ra * 32 + ca * 8);
            int rb = wn * 64 + i * 16 + lr;
            int cb = (lc + (rb >> 1)) & 3;
            bfr[i] = *(const bf16x8*)(Bs + rb * 32 + cb * 8);
        }
        #pragma unroll
        for (int i = 0; i < 4; i++)
            #pragma unroll
            for (int j = 0; j < 4; j++)
                acc[i][j] = __builtin_amdgcn_mfma_f32_16x16x32_bf16(
                    af[i], bfr[j], acc[i][j], 0, 0, 0);
    }

    #pragma unroll
    for (int j = 0; j < 4; j++) {
        int n = bx * 128 + wn * 64 + j * 16 + lr;
        float bv = bias[n];
        #pragma unroll
        for (int i = 0; i < 4; i++) {
            int m0 = by * 128 + wm * 64 + i * 16 + lc * 4;
            #pragma unroll
            for (int e = 0; e < 4; e++) {
                float t = acc[i][j][e] + bv;
                if (EPI == 1) t = 0.5f * t * (1.0f + erff(t * 0.70710678118654752f));
                if (EPI == 2) t += R[(size_t)(m0 + e) * N + n];
                Cm[(size_t)(m0 + e) * N + n] = (OutT)t;
            }
        }
    }
}

// ---------------------------------------------------------------------------
// MFMA flash attention: one block per (b,h,qtile of 64). 4 waves; wave w owns
// q rows w*16..w*16+16. Q A-frags direct global->reg (once). K staged via
// swizzled global_load_lds; V transposed into LDS; P round-trips via LDS
// (C-layout -> A-layout). Online softmax state per lane-row (quad*4+e).
// qt permuted (long blocks first, rotated by h+b) for CU load balance.
// ---------------------------------------------------------------------------
__global__ __launch_bounds__(256, 3) void attn_mfma(
    const __bf16* __restrict__ qkv, const int* __restrict__ amask,
    __bf16* __restrict__ ybuf, float* __restrict__ mbuf, float* __restrict__ lbuf)
{
    __shared__ __bf16 Kb[2][64 * 32];               // swizzled halves, 8 KB
    __shared__ __align__(16) __bf16 Vt[64][72];     // V^T [d][k], 9216 B
    __shared__ __align__(16) __bf16 Ps[64][72];     // P   [q][k], 9216 B

    int blk = blockIdx.x;
    int idx = blk & 15, h = (blk >> 4) & 15, b = blk >> 8;
    int idx2 = (idx + h + b) & 15;
    int p2 = idx2 >> 1;
    int qt = (idx2 & 1) ? p2 : (15 - p2);           // descending-ish work
    int q0 = qt * 64;

    int tid = threadIdx.x, wave = tid >> 6, lane = tid & 63;
    int quad = lane >> 4, l15 = lane & 15;
    const int srow = lane >> 2, cphys = lane & 3;
    const size_t RS = 3 * Cc;                       // qkv row stride (elems)
    const size_t bT = (size_t)b * Tc;

    // Q A-frags: rows wave*16 + l15, k = quad*8 (+32 for half 1)
    bf16x8 qf[2];
    {
        const __bf16* qrow = qkv + (bT + q0 + wave * 16 + l15) * RS + h * 64 + quad * 8;
        qf[0] = *(const bf16x8*)qrow;
        qf[1] = *(const bf16x8*)(qrow + 32);
    }

    float m_i[4], l_i[4];
    f32x4 Oacc[4] = {};
    #pragma unroll
    for (int e = 0; e < 4; e++) { m_i[e] = -INFINITY; l_i[e] = 0.f; }

    for (int kt = 0; kt <= qt; kt++) {
        int k0 = kt * 64;
        __syncthreads();                            // prev Kb/Vt/Ps reads done

        // Stage K tile (wave w loads rows w*16..+16, both halves, swizzled)
        #pragma unroll
        for (int c = 0; c < 2; c++) {
            int rloc = wave * 16 + srow;
            int clog = (cphys - (rloc >> 1)) & 3;
            const __bf16* g = qkv + (bT + k0 + rloc) * RS + Cc + h * 64 + c * 32 + clog * 8;
            __builtin_amdgcn_global_load_lds(
                (const __attribute__((address_space(1))) void*)g,
                (__attribute__((address_space(3))) void*)(&Kb[c][wave * 512]), 16, 0, 0);
        }
        // Stage V transposed: thread (wave,lane) covers k=lane, d=wave*16..+16
        {
            int kk = lane, dbase = wave * 16;
            const __bf16* vrow = qkv + (bT + k0 + kk) * RS + 2 * Cc + h * 64 + dbase;
            bf16x8 v0 = *(const bf16x8*)vrow;
            bf16x8 v1 = *(const bf16x8*)(vrow + 8);
            #pragma unroll
            for (int j = 0; j < 8; j++) Vt[dbase + j][kk] = v0[j];
            #pragma unroll
            for (int j = 0; j < 8; j++) Vt[dbase + 8 + j][kk] = v1[j];
        }
        int am4[4];
        #pragma unroll
        for (int j = 0; j < 4; j++) am4[j] = amask[bT + k0 + j * 16 + l15];
        __syncthreads();

        // S = Q K^T : C col = k (j*16+l15), row = q (quad*4+e)
        f32x4 Sacc[4] = {};
        #pragma unroll
        for (int c = 0; c < 2; c++)
            #pragma unroll
            for (int j = 0; j < 4; j++) {
                int rb = j * 16 + l15;
                int cb = (quad + (rb >> 1)) & 3;
                bf16x8 kf = *(const bf16x8*)(&Kb[c][rb * 32 + cb * 8]);
                Sacc[j] = __builtin_amdgcn_mfma_f32_16x16x32_bf16(qf[c], kf, Sacc[j], 0, 0, 0);
            }

        // Online softmax + write P (bf16) to LDS
        #pragma unroll
        for (int e = 0; e < 4; e++) {
            int qg = q0 + wave * 16 + quad * 4 + e;
            float sv[4], rmax = -INFINITY;
            #pragma unroll
            for (int j = 0; j < 4; j++) {
                int kg = k0 + j * 16 + l15;
                sv[j] = (kg <= qg && am4[j] != 0) ? Sacc[j][e] * 0.125f : -INFINITY;
                rmax = fmaxf(rmax, sv[j]);
            }
            #pragma unroll
            for (int off = 8; off; off >>= 1)
                rmax = fmaxf(rmax, __shfl_xor(rmax, off, 64));
            float mnew = fmaxf(m_i[e], rmax);
            float alpha = (m_i[e] == -INFINITY) ? 0.f : __expf(m_i[e] - mnew);
            float rsum = 0.f, pj[4];
            #pragma unroll
            for (int j = 0; j < 4; j++) {
                pj[j] = (sv[j] == -INFINITY) ? 0.f : __expf(sv[j] - mnew);
                rsum += pj[j];
            }
            #pragma unroll
            for (int off = 8; off; off >>= 1)
                rsum += __shfl_xor(rsum, off, 64);
            l_i[e] = alpha * l_i[e] + rsum;
            m_i[e] = mnew;
            #pragma unroll
            for (int j2 = 0; j2 < 4; j2++) Oacc[j2][e] *= alpha;
            #pragma unroll
            for (int j = 0; j < 4; j++)
                Ps[wave * 16 + quad * 4 + e][j * 16 + l15] = (__bf16)pj[j];
        }
        __syncthreads();                            // P visible

        // O += P V : A = Ps rows q, B = Vt rows d
        #pragma unroll
        for (int c2 = 0; c2 < 2; c2++) {
            bf16x8 pa = *(const bf16x8*)(&Ps[wave * 16 + l15][quad * 8 + c2 * 32]);
            #pragma unroll
            for (int j2 = 0; j2 < 4; j2++) {
                bf16x8 vb = *(const bf16x8*)(&Vt[j2 * 16 + l15][quad * 8 + c2 * 32]);
                Oacc[j2] = __builtin_amdgcn_mfma_f32_16x16x32_bf16(pa, vb, Oacc[j2], 0, 0, 0);
            }
        }
    }

    // Epilogue: y = O/l (bf16), save m,l
    #pragma unroll
    for (int e = 0; e < 4; e++) {
        int qg = q0 + wave * 16 + quad * 4 + e;
        float invl = (l_i[e] > 0.f) ? 1.f / l_i[e] : 0.f;
        #pragma unroll
        for (int j2 = 0; j2 < 4; j2++)
            ybuf[(bT + qg) * Cc + h * 64 + j2 * 16 + l15] = (__bf16)(Oacc[j2][e] * invl);
        if (l15 == 0) {
            mbuf[(size_t)(b * Hc + h) * Tc + qg] = m_i[e];
            lbuf[(size_t)(b * Hc + h) * Tc + qg] = l_i[e];
        }
    }
}

// ---------------------------------------------------------------------------
// MFMA imp pass: one block per (b,h,ktile of 64). S^T = K Q^T via MFMA
// (A=K rows -> C row=k, B=Q rows -> C col=q); accumulate exp(s-m_q)/l_q
// over q>=k; one atomicAdd per k row at the end. kt permuted for balance.
// ---------------------------------------------------------------------------
__global__ __launch_bounds__(256, 4) void imp_mfma(
    const __bf16* __restrict__ qkv, const int* __restrict__ amask,
    const float* __restrict__ mbuf, const float* __restrict__ lbuf,
    float* __restrict__ impbuf)
{
    __shared__ __bf16 Qb[2][64 * 32];               // swizzled halves, 8 KB
    __shared__ float mls[64], rls[64];

    int blk = blockIdx.x;
    int idx = blk & 15, h = (blk >> 4) & 15, b = blk >> 8;
    int idx2 = (idx + h + b) & 15;
    int p2 = idx2 >> 1;
    int kt = (idx2 & 1) ? (15 - p2) : p2;           // descending-ish work
    int k0 = kt * 64;

    int tid = threadIdx.x, wave = tid >> 6, lane = tid & 63;
    int quad = lane >> 4, l15 = lane & 15;
    const int srow = lane >> 2, cphys = lane & 3;
    const size_t RS = 3 * Cc;
    const size_t bT = (size_t)b * Tc;
    const size_t mlrow = (size_t)(b * Hc + h) * Tc;

    // K A-frags direct: rows wave*16 + l15
    bf16x8 kf[2];
    {
        const __bf16* krow = qkv + (bT + k0 + wave * 16 + l15) * RS + Cc + h * 64 + quad * 8;
        kf[0] = *(const bf16x8*)krow;
        kf[1] = *(const bf16x8*)(krow + 32);
    }
    int amk[4];
    #pragma unroll
    for (int e = 0; e < 4; e++) amk[e] = amask[bT + k0 + wave * 16 + quad * 4 + e];

    float sums[4] = {0.f, 0.f, 0.f, 0.f};

    for (int qt = kt; qt < 16; qt++) {
        int q0 = qt * 64;
        __syncthreads();
        #pragma unroll
        for (int c = 0; c < 2; c++) {
            int rloc = wave * 16 + srow;
            int clog = (cphys - (rloc >> 1)) & 3;
            const __bf16* g = qkv + (bT + q0 + rloc) * RS + h * 64 + c * 32 + clog * 8;
            __builtin_amdgcn_global_load_lds(
                (const __attribute__((address_space(1))) void*)g,
                (__attribute__((address_space(3))) void*)(&Qb[c][wave * 512]), 16, 0, 0);
        }
        if (tid < 64) {
            float l = lbuf[mlrow + q0 + tid];
            mls[tid] = mbuf[mlrow + q0 + tid];
            rls[tid] = (l > 0.f) ? 1.f / l : 0.f;
        }
        __syncthreads();

        f32x4 Sacc[4] = {};
        #pragma unroll
        for (int c = 0; c < 2; c++)
            #pragma unroll
            for (int j = 0; j < 4; j++) {
                int rb = j * 16 + l15;
                int cb = (quad + (rb >> 1)) & 3;
                bf16x8 qb = *(const bf16x8*)(&Qb[c][rb * 32 + cb * 8]);
                Sacc[j] = __builtin_amdgcn_mfma_f32_16x16x32_bf16(kf[c], qb, Sacc[j], 0, 0, 0);
            }

        #pragma unroll
        for (int j = 0; j < 4; j++) {
            int qg = q0 + j * 16 + l15;
            float ml = mls[j * 16 + l15], rl = rls[j * 16 + l15];
            #pragma unroll
            for (int e = 0; e < 4; e++) {
                int kg = k0 + wave * 16 + quad * 4 + e;
                if (kg <= qg && amk[e] != 0 && rl > 0.f)
                    sums[e] += __expf(Sacc[j][e] * 0.125f - ml) * rl;
            }
        }
    }

    #pragma unroll
    for (int e = 0; e < 4; e++) {
        float s = sums[e];
        #pragma unroll
        for (int off = 8; off; off >>= 1) s += __shfl_xor(s, off, 64);
        if (l15 == 0)
            atomicAdd(&impbuf[bT + k0 + wave * 16 + quad * 4 + e], s);
    }
}

// ---------------------------------------------------------------------------
// Finalize: scale raw sums by 1/H and pos_norm, global max, sinks, mask.
// ---------------------------------------------------------------------------
__global__ __launch_bounds__(1024) void finalize_kernel(
    const float* __restrict__ impbuf, const int* __restrict__ amask,
    const float* __restrict__ thr, float* __restrict__ out_mask,
    float* __restrict__ out_imp)
{
    __shared__ float red[16];
    int tid = threadIdx.x;
    float vloc[4];
    float gmax = -INFINITY;
    #pragma unroll
    for (int it = 0; it < 4; it++) {
        int i = tid + it * 1024;
        int tt = i % Tc;
        float posn = (float)(Tc - tt) / (float)Tc;
        float v = impbuf[i] * (1.0f / Hc) / (posn + 1e-8f);
        vloc[it] = v;
        gmax = fmaxf(gmax, v);
    }
    for (int off = 32; off; off >>= 1) gmax = fmaxf(gmax, __shfl_down(gmax, off, 64));
    if ((tid & 63) == 0) red[tid >> 6] = gmax;
    __syncthreads();
    float gm = red[0];
    #pragma unroll
    for (int i = 1; i < 16; i++) gm = fmaxf(gm, red[i]);

    float t = thr[0];
    #pragma unroll
    for (int it = 0; it < 4; it++) {
        int i = tid + it * 1024;
        int tt = i % Tc;
        float v = vloc[it];
        if (tt < SINKc) v = gm + 1.0f;
        float mk = (v >= t) ? 1.f : 0.f;
        if (tt < SINKc) mk = 1.f;
        mk *= (float)amask[i];
        out_imp[i]  = v;
        out_mask[i] = mk;
    }
}

// ---------------------------------------------------------------------------
extern "C" void kernel_launch(void* const* d_in, const int* in_sizes, int n_in,
                              void* d_out, int out_size, void* d_ws, size_t ws_size,
                              hipStream_t stream)
{
    const float* x      = (const float*)d_in[0];
    const int*   amask  = (const int*)  d_in[1];
    const float* W_attn = (const float*)d_in[2];
    const float* b_attn = (const float*)d_in[3];
    const float* W_proj = (const float*)d_in[4];
    const float* b_proj = (const float*)d_in[5];
    const float* ln1w   = (const float*)d_in[6];
    const float* ln1b   = (const float*)d_in[7];
    const float* ln2w   = (const float*)d_in[8];
    const float* ln2b   = (const float*)d_in[9];
    const float* W_fc   = (const float*)d_in[10];
    const float* b_fc   = (const float*)d_in[11];
    const float* W_fc2  = (const float*)d_in[12];
    const float* b_fc2  = (const float*)d_in[13];
    const float* thr    = (const float*)d_in[14];

    float* out      = (float*)d_out;                 // (B,T,C)
    float* out_mask = out + (size_t)Bc * Tc * Cc;    // (B,T)
    float* out_imp  = out_mask + (size_t)Bc * Tc;    // (B,T)

    // Workspace layout (byte offsets; all 16B-aligned)
    char* wsb = (char*)d_ws;
    __bf16* qkvbf = (__bf16*)wsb;                       // 25,165,824 B
    __bf16* hbf   = (__bf16*)(wsb + 25165824);          //  8,388,608 B
    __bf16* ybf   = (__bf16*)(wsb + 33554432);          //  8,388,608 B
    __bf16* fcbf  = (__bf16*)(wsb + 41943040);          // 33,554,432 B
    __bf16* WaT   = (__bf16*)(wsb + 75497472);          //  6,291,456 B
    __bf16* WpT   = (__bf16*)(wsb + 81788928);          //  2,097,152 B
    __bf16* WfT   = (__bf16*)(wsb + 83886080);          //  8,388,608 B
    __bf16* Wf2T  = (__bf16*)(wsb + 92274688);          //  8,388,608 B
    float*  mbuf  = (float*)(wsb + 100663296);          //    262,144 B
    float*  lbuf  = (float*)(wsb + 100925440);          //    262,144 B
    float*  impb  = (float*)(wsb + 101187584);          //     16,384 B

    const int M = Bc * Tc;   // 4096

    // Weight transpose+convert: W[K][N] -> Wt[N][K] bf16
    transpose_bf16<<<dim3(3*Cc/32, Cc/32), 256, 0, stream>>>(W_attn, WaT, Cc, 3*Cc);
    transpose_bf16<<<dim3(Cc/32,   Cc/32), 256, 0, stream>>>(W_proj, WpT, Cc, Cc);
    transpose_bf16<<<dim3(4*Cc/32, Cc/32), 256, 0, stream>>>(W_fc,   WfT, Cc, 4*Cc);
    transpose_bf16<<<dim3(Cc/32, 4*Cc/32), 256, 0, stream>>>(W_fc2,  Wf2T, 4*Cc, Cc);

    // h = ln1(x) -> bf16
    ln_kernel<<<M, 256, 0, stream>>>(x, ln1w, ln1b, hbf);
    // qkv = h @ W_attn + b_attn  -> bf16   (1-D swizzled grid)
    gemm_bf16<0, __bf16><<<(3*Cc/128) * (M/128), 256, 0, stream>>>(
        hbf, WaT, b_attn, nullptr, qkvbf, M, 3*Cc, Cc);
    // zero the imp accumulator
    hipMemsetAsync(impb, 0, (size_t)Bc * Tc * sizeof(float), stream);
    // attention -> y (bf16), (m,l)
    attn_mfma<<<Bc * Hc * 16, 256, 0, stream>>>(qkvbf, amask, ybf, mbuf, lbuf);
    // x2 = x + y @ W_proj + b_proj   (into d_out, fp32)
    gemm_bf16<2, float><<<(Cc/128) * (M/128), 256, 0, stream>>>(
        ybf, WpT, b_proj, x, out, M, Cc, Cc);
    // imp accumulation (needs mbuf/lbuf)
    imp_mfma<<<Bc * Hc * 16, 256, 0, stream>>>(qkvbf, amask, mbuf, lbuf, impb);
    // m = ln2(x2) -> bf16 (reuse hbf)
    ln_kernel<<<M, 256, 0, stream>>>(out, ln2w, ln2b, hbf);
    // fc = gelu(m @ W_fc + b_fc) -> bf16
    gemm_bf16<1, __bf16><<<(4*Cc/128) * (M/128), 256, 0, stream>>>(
        hbf, WfT, b_fc, nullptr, fcbf, M, 4*Cc, Cc);
    // out = x2 + fc @ W_fc2 + b_fc2   (in-place residual from d_out)
    gemm_bf16<2, float><<<(Cc/128) * (M/128), 256, 0, stream>>>(
        fcbf, Wf2T, b_fc2, out, out, M, Cc, 4*Cc);
    // mask & imp outputs
    finalize_kernel<<<1, 1024, 0, stream>>>(impb, amask, thr, out_mask, out_imp);
}